// Round 1
// baseline (987.295 us; speedup 1.0000x reference)
//
#include <hip/hip_runtime.h>
#include <math.h>

#define NB 4
#define NC 50
#define NIMG 64
#define NN 4096
#define QS 52   // padded row stride for q/k/v (16B-aligned rows, pads zeroed)

static constexpr float F_SCALE = 0.14142135623730951f; // 50^-0.5
static constexpr float F_DT = 0.001f;

// ---- workspace layout (floats) ----
static constexpr size_t OFF_XI  = 0;                         // [B][C][64][64]
static constexpr size_t SZ_XI   = (size_t)NB*NC*NN;          // 819200
static constexpr size_t OFF_T1  = OFF_XI + SZ_XI;            // [3][B][C][62][62]
static constexpr size_t SZ_T1   = (size_t)3*NB*NC*62*62;     // 2306400
static constexpr size_t OFF_QKV = OFF_T1 + SZ_T1;            // [3][B][4096][52]
static constexpr size_t SZ_QKV  = (size_t)3*NB*NN*QS;        // 2555904
static constexpr size_t OFF_LP  = OFF_QKV + SZ_QKV;          // [8][B*4096]
static constexpr size_t SZ_LP   = (size_t)8*NB*NN;
static constexpr size_t OFF_L   = OFF_LP + SZ_LP;            // [B*4096]
static constexpr size_t SZ_L    = (size_t)NB*NN;
static constexpr size_t OFF_S   = OFF_L + SZ_L;              // [B][64][4096]
static constexpr size_t SZ_S    = (size_t)NB*64*NN;
static constexpr size_t OFF_BS  = OFF_S + SZ_S;              // [B][64][4096]
// total ~ 30.2 MiB of ws

__device__ __forceinline__ void load52(float* a, const float4* __restrict__ b4) {
#pragma unroll
  for (int d4 = 0; d4 < 13; ++d4) {
    float4 v = b4[d4];
    a[d4*4+0] = v.x; a[d4*4+1] = v.y; a[d4*4+2] = v.z; a[d4*4+3] = v.w;
  }
}

__device__ __forceinline__ float dot52(const float* __restrict__ a,
                                       const float4* __restrict__ b4) {
  float dot = 0.f;
#pragma unroll
  for (int d4 = 0; d4 < 13; ++d4) {
    float4 v = b4[d4];
    dot += a[d4*4+0]*v.x + a[d4*4+1]*v.y + a[d4*4+2]*v.z + a[d4*4+3]*v.w;
  }
  return dot;
}

// ---------------- K0: transpose x (B,N,C) -> xi (B,C,64,64) ----------------
__global__ __launch_bounds__(256) void k_transpose(const float* __restrict__ x,
                                                   float* __restrict__ xi) {
  __shared__ float tile[64][51];
  int b = blockIdx.x >> 6, nt = blockIdx.x & 63;
  int n0 = nt * 64;
  const float* src = x + ((size_t)b*NN + n0) * NC;   // 3200 contiguous floats
  for (int i = threadIdx.x; i < 64*NC; i += 256) tile[i/NC][i%NC] = src[i];
  __syncthreads();
  for (int i = threadIdx.x; i < NC*64; i += 256) {
    int c = i >> 6, nn = i & 63;
    xi[((size_t)b*NC + c)*NN + n0 + nn] = tile[nn][c];
  }
}

// ---------------- K1: conv1 (5x5, pad top2/right2) + BN -> t1 ----------------
// grid (16 tiles, 12 p*b, 5 o-groups of 10), block 256 = 16x16 pixels
__global__ __launch_bounds__(256) void k_conv1(const float* __restrict__ xi,
                                               const float* __restrict__ w1,
                                               const float* __restrict__ g,
                                               const float* __restrict__ be,
                                               const float* __restrict__ mu,
                                               const float* __restrict__ va,
                                               float* __restrict__ t1) {
  __shared__ float sin1[20][20];
  int tile = blockIdx.x;
  int i0 = (tile >> 2) * 16, j0 = (tile & 3) * 16;
  int pb = blockIdx.y; int p = pb >> 2, b = pb & 3;
  int o0 = blockIdx.z * 10;
  int tx = threadIdx.x & 15, ty = threadIdx.x >> 4;

  float acc[10];
#pragma unroll
  for (int o = 0; o < 10; ++o) acc[o] = 0.f;

  const float* xib = xi + (size_t)b*NC*NN;
  const float* wp  = w1 + (size_t)p*62500;    // [o][c][25]

  for (int c = 0; c < NC; ++c) {
    __syncthreads();
    for (int idx = threadIdx.x; idx < 400; idx += 256) {
      int ry = idx / 20, rx = idx % 20;
      int y = i0 - 2 + ry, xx = j0 + rx;
      float v = 0.f;
      if (y >= 0 && y < 64 && xx < 64) v = xib[(size_t)c*NN + y*64 + xx];
      sin1[ry][rx] = v;
    }
    __syncthreads();
    float iv[25];
#pragma unroll
    for (int dy = 0; dy < 5; ++dy)
#pragma unroll
      for (int dx = 0; dx < 5; ++dx)
        iv[dy*5+dx] = sin1[ty+dy][tx+dx];
    const float* wc = wp + c*25;
#pragma unroll
    for (int o = 0; o < 10; ++o) {
      const float* wo = wc + (size_t)(o0+o)*1250;   // uniform -> s_load
      float a = acc[o];
#pragma unroll
      for (int k = 0; k < 25; ++k) a += iv[k]*wo[k];
      acc[o] = a;
    }
  }

  int i = i0 + ty, j = j0 + tx;
  if (i < 62 && j < 62) {
#pragma unroll
    for (int o = 0; o < 10; ++o) {
      int oc = o0 + o;
      float sc = g[p*NC+oc] * rsqrtf(va[p*NC+oc] + 1e-5f);
      float sh = be[p*NC+oc] - mu[p*NC+oc]*sc;
      t1[((size_t)(p*NB+b)*NC + oc)*3844 + i*62 + j] = acc[o]*sc + sh;
    }
  }
}

// ---------------- K2: conv2 (2x2, pad top3/right3) -> qkv [p][b][n][52] ----------------
// grid (16 tiles, 12 p*b, 2 o-groups of 25), block 256
__global__ __launch_bounds__(256) void k_conv2(const float* __restrict__ t1,
                                               const float* __restrict__ w2,
                                               float* __restrict__ qkv) {
  __shared__ float sin2[17][17];
  int tile = blockIdx.x;
  int h0 = (tile >> 2) * 16, w0 = (tile & 3) * 16;
  int pb = blockIdx.y; int p = pb >> 2, b = pb & 3;
  int og = blockIdx.z; int o0 = og * 25;
  int tx = threadIdx.x & 15, ty = threadIdx.x >> 4;

  float acc[25];
#pragma unroll
  for (int o = 0; o < 25; ++o) acc[o] = 0.f;

  const float* tb = t1 + (size_t)(p*NB+b)*NC*3844;
  const float* wp = w2 + (size_t)p*10000;     // [o][c][4]

  for (int c = 0; c < NC; ++c) {
    __syncthreads();
    for (int idx = threadIdx.x; idx < 289; idx += 256) {
      int ry = idx / 17, rx = idx % 17;
      int y = h0 - 3 + ry, xx = w0 + rx;
      float v = 0.f;
      if (y >= 0 && y < 62 && xx < 62) v = tb[(size_t)c*3844 + y*62 + xx];
      sin2[ry][rx] = v;
    }
    __syncthreads();
    float i00 = sin2[ty][tx],   i01 = sin2[ty][tx+1];
    float i10 = sin2[ty+1][tx], i11 = sin2[ty+1][tx+1];
    const float* wc = wp + c*4;
#pragma unroll
    for (int o = 0; o < 25; ++o) {
      const float* wo = wc + (size_t)(o0+o)*200;    // uniform -> s_load
      acc[o] += i00*wo[0] + i01*wo[1] + i10*wo[2] + i11*wo[3];
    }
  }

  int h = h0 + ty, w = w0 + tx;
  int n = h*64 + w;
  float* dst = qkv + ((size_t)(p*NB+b)*NN + n)*QS;
#pragma unroll
  for (int o = 0; o < 25; ++o) dst[o0+o] = acc[o];
  if (og == 1) { dst[50] = 0.f; dst[51] = 0.f; }   // zero pads (replace ws poison)
}

// ---------------- K3a: row softmax denominators (partial) ----------------
// grid (16 rowblocks, 8 j-chunks, 4 b), block 256; lane owns a row, q in VGPRs,
// k rows read with wave-uniform addresses (s_load path).
__global__ __launch_bounds__(256) void k_Lpart(const float* __restrict__ qkv,
                                               float* __restrict__ Lpart) {
  int t  = blockIdx.x * 256 + threadIdx.x;
  int jc = blockIdx.y, b = blockIdx.z;
  float q[52];
  load52(q, (const float4*)(qkv + ((size_t)b*NN + t)*QS));
  const float* Kb = qkv + ((size_t)NB*NN + (size_t)b*NN)*QS;
  float s = 0.f;
  for (int jj = 0; jj < 512; ++jj) {
    size_t j = (size_t)jc*512 + jj;
    float dot = dot52(q, (const float4*)(Kb + j*QS));
    s += __expf(dot * F_SCALE);
  }
  Lpart[(size_t)jc*(NB*NN) + (size_t)b*NN + t] = s;
}

__global__ __launch_bounds__(256) void k_Lred(const float* __restrict__ Lpart,
                                              float* __restrict__ L) {
  int i = blockIdx.x * 256 + threadIdx.x;   // 16384
  float s = 0.f;
#pragma unroll
  for (int jc = 0; jc < 8; ++jc) s += Lpart[(size_t)jc*(NB*NN) + i];
  L[i] = s;
}

// ---------------- K3b: block-local column sums of r ----------------
// grid (64 rowblocks, 4 j-groups, 4 b), block 1024; lane owns a column, k in VGPRs.
__global__ __launch_bounds__(1024) void k_S(const float* __restrict__ qkv,
                                            const float* __restrict__ L,
                                            float* __restrict__ S) {
  int blk = blockIdx.x, wgj = blockIdx.y, b = blockIdx.z;
  int j = wgj * 1024 + threadIdx.x;
  float kreg[52];
  load52(kreg, (const float4*)(qkv + ((size_t)NB*NN + (size_t)b*NN + j)*QS));
  const float* Qb = qkv + (size_t)b*NN*QS;
  const float* Lb = L + (size_t)b*NN;
  float sacc = 0.f;
  for (int tt = 0; tt < 64; ++tt) {
    int t = blk*64 + tt;
    float dot = dot52(kreg, (const float4*)(Qb + (size_t)t*QS));  // q uniform
    float e = __expf(dot * F_SCALE);
    sacc += e / Lb[t];
  }
  S[((size_t)b*64 + blk)*NN + j] = sacc;
}

// ---------------- scan over row-blocks (exclusive) ----------------
__global__ __launch_bounds__(256) void k_scan(const float* __restrict__ S,
                                              float* __restrict__ base) {
  int i = blockIdx.x * 256 + threadIdx.x;   // b*4096 + j
  int b = i >> 12, j = i & 4095;
  float run = 0.f;
  for (int blk = 0; blk < 64; ++blk) {
    size_t idx = ((size_t)b*64 + blk)*NN + j;
    base[idx] = run;
    run += S[idx];
  }
}

__global__ __launch_bounds__(1024) void k_zero(float* __restrict__ out) {
  size_t i = (size_t)blockIdx.x * 1024 + threadIdx.x;
  if (i < (size_t)NB*NN*NC) out[i] = 0.f;
}

// ---------------- K4: spikes + sparse attn@V ----------------
__global__ __launch_bounds__(1024) void k_spike(const float* __restrict__ qkv,
                                                const float* __restrict__ L,
                                                const float* __restrict__ base,
                                                float* __restrict__ out) {
  int blk = blockIdx.x, wgj = blockIdx.y, b = blockIdx.z;
  int j = wgj * 1024 + threadIdx.x;
  float kreg[52];
  load52(kreg, (const float4*)(qkv + ((size_t)NB*NN + (size_t)b*NN + j)*QS));
  const float* Qb = qkv + (size_t)b*NN*QS;
  const float* Lb = L + (size_t)b*NN;
  const float* V  = qkv + ((size_t)2*NB*NN + (size_t)b*NN + j)*QS;

  float cum = F_DT * base[((size_t)b*64 + blk)*NN + j];
  float Fprev = floorf(cum);
  for (int tt = 0; tt < 64; ++tt) {
    int t = blk*64 + tt;
    float dot = dot52(kreg, (const float4*)(Qb + (size_t)t*QS));
    float r = __expf(dot * F_SCALE) / Lb[t];
    cum += r * F_DT;
    float F = floorf(cum);
    if (F > Fprev) {                       // spike: add (F-Fprev)/dt * V[j,:]
      float sv = (F - Fprev) / F_DT;
      float* orow = out + ((size_t)b*NN + t)*NC;
      for (int d = 0; d < NC; ++d) atomicAdd(orow + d, sv * V[d]);
      Fprev = F;
    }
  }
}

extern "C" void kernel_launch(void* const* d_in, const int* in_sizes, int n_in,
                              void* d_out, int out_size, void* d_ws, size_t ws_size,
                              hipStream_t stream) {
  const float* x  = (const float*)d_in[0];
  const float* w1 = (const float*)d_in[1];
  const float* w2 = (const float*)d_in[2];
  const float* g  = (const float*)d_in[3];
  const float* be = (const float*)d_in[4];
  const float* mu = (const float*)d_in[5];
  const float* va = (const float*)d_in[6];
  float* out = (float*)d_out;
  float* ws  = (float*)d_ws;

  float* xi   = ws + OFF_XI;
  float* t1   = ws + OFF_T1;
  float* qkv  = ws + OFF_QKV;
  float* Lp   = ws + OFF_LP;
  float* L    = ws + OFF_L;
  float* S    = ws + OFF_S;
  float* base = ws + OFF_BS;

  k_transpose<<<dim3(256), dim3(256), 0, stream>>>(x, xi);
  k_conv1<<<dim3(16, 12, 5), dim3(256), 0, stream>>>(xi, w1, g, be, mu, va, t1);
  k_conv2<<<dim3(16, 12, 2), dim3(256), 0, stream>>>(t1, w2, qkv);
  k_Lpart<<<dim3(16, 8, 4), dim3(256), 0, stream>>>(qkv, Lp);
  k_Lred<<<dim3(64), dim3(256), 0, stream>>>(Lp, L);
  k_S<<<dim3(64, 4, 4), dim3(1024), 0, stream>>>(qkv, L, S);
  k_scan<<<dim3(64), dim3(256), 0, stream>>>(S, base);
  k_zero<<<dim3(800), dim3(1024), 0, stream>>>(out);
  k_spike<<<dim3(64, 4, 4), dim3(1024), 0, stream>>>(qkv, L, base, out);
}

// Round 2
// 552.515 us; speedup vs baseline: 1.7869x; 1.7869x over previous
//
#include <hip/hip_runtime.h>
#include <hip/hip_bf16.h>
#include <math.h>

#define NB 4
#define NC 50
#define NN 4096
#define QS 52   // padded f32 row stride for qkv

typedef __attribute__((ext_vector_type(8))) short short8;
typedef __attribute__((ext_vector_type(4))) float f32x4;

static constexpr float F_SCALE = 0.14142135623730951f; // 50^-0.5 (folded into q_bf16)
static constexpr float F_DT = 0.001f;

// ---- workspace layout (float units) ----
static constexpr size_t OFF_XI  = 0;                          // [B][C][64][64] f32
static constexpr size_t SZ_XI   = (size_t)NB*NC*NN;           // 819200
static constexpr size_t OFF_T1  = OFF_XI + SZ_XI;             // [3][B][C][62][62] f32 (BN'd)
static constexpr size_t SZ_T1   = (size_t)3*NB*NC*62*62;      // 2306400
static constexpr size_t OFF_QKV = OFF_T1 + SZ_T1;             // [3][B][4096][52] f32
static constexpr size_t SZ_QKV  = (size_t)3*NB*NN*QS;         // 2555904
static constexpr size_t OFF_QB  = OFF_QKV + SZ_QKV;           // [B][4096][64] bf16 (scaled)
static constexpr size_t SZ_QB   = (size_t)NB*NN*64/2;         // 524288 f32-equiv
static constexpr size_t OFF_KB  = OFF_QB + SZ_QB;             // [B][4096][64] bf16
static constexpr size_t SZ_KB   = SZ_QB;
static constexpr size_t OFF_LP  = OFF_KB + SZ_KB;             // [4][B*4096]
static constexpr size_t SZ_LP   = (size_t)4*NB*NN;
static constexpr size_t OFF_L   = OFF_LP + SZ_LP;             // [B*4096]
static constexpr size_t SZ_L    = (size_t)NB*NN;
static constexpr size_t OFF_LI  = OFF_L + SZ_L;               // [B*4096] 1/L
static constexpr size_t SZ_LI   = SZ_L;
static constexpr size_t OFF_CP  = OFF_LI + SZ_LI;             // [4][B*4096]
static constexpr size_t SZ_CP   = (size_t)4*NB*NN;
static constexpr size_t OFF_CT  = OFF_CP + SZ_CP;             // [B*4096]
// total ~27.6 MB

__device__ __forceinline__ void load52(float* a, const float4* __restrict__ b4) {
#pragma unroll
  for (int d4 = 0; d4 < 13; ++d4) {
    float4 v = b4[d4];
    a[d4*4+0] = v.x; a[d4*4+1] = v.y; a[d4*4+2] = v.z; a[d4*4+3] = v.w;
  }
}

__device__ __forceinline__ float dot52(const float* __restrict__ a,
                                       const float4* __restrict__ b4) {
  float dot = 0.f;
#pragma unroll
  for (int d4 = 0; d4 < 13; ++d4) {
    float4 v = b4[d4];
    dot += a[d4*4+0]*v.x + a[d4*4+1]*v.y + a[d4*4+2]*v.z + a[d4*4+3]*v.w;
  }
  return dot;
}

// ---------------- K0: transpose x (B,N,C) -> xi (B,C,64,64) ----------------
__global__ __launch_bounds__(256) void k_transpose(const float* __restrict__ x,
                                                   float* __restrict__ xi) {
  __shared__ float tile[64][51];
  int b = blockIdx.x >> 6, nt = blockIdx.x & 63;
  int n0 = nt * 64;
  const float* src = x + ((size_t)b*NN + n0) * NC;
  for (int i = threadIdx.x; i < 64*NC; i += 256) tile[i/NC][i%NC] = src[i];
  __syncthreads();
  for (int i = threadIdx.x; i < NC*64; i += 256) {
    int c = i >> 6, nn = i & 63;
    xi[((size_t)b*NC + c)*NN + n0 + nn] = tile[nn][c];
  }
}

// ---------------- K1: conv1 5x5 (pad top2/right2) + BN -> t1 ----------------
// grid (16 tiles, 12 p*b, 2 o-groups of 25), block 256; 2-deep channel pipeline
__global__ __launch_bounds__(256) void k_conv1(const float* __restrict__ xi,
                                               const float* __restrict__ w1,
                                               const float* __restrict__ g,
                                               const float* __restrict__ be,
                                               const float* __restrict__ mu,
                                               const float* __restrict__ va,
                                               float* __restrict__ t1) {
  __shared__ float s[20][24];   // stride 24: 2-way bank aliasing only (free)
  int tile = blockIdx.x;
  int i0 = (tile >> 2) * 16, j0 = (tile & 3) * 16;
  int pb = blockIdx.y; int p = pb >> 2, b = pb & 3;
  int o0 = blockIdx.z * 25;
  int tx = threadIdx.x & 15, ty = threadIdx.x >> 4;

  const float* xib = xi + (size_t)b*NC*NN;
  const float* wp  = w1 + (size_t)p*62500 + (size_t)o0*1250;  // [o][c][25]

  float acc[25];
#pragma unroll
  for (int o = 0; o < 25; ++o) acc[o] = 0.f;

  // prefetch address setup: 400 tile elems, 2 per thread (2nd masked)
  int e0 = threadIdx.x, e1 = threadIdx.x + 256;
  int ry0 = e0/20, rx0 = e0%20, ry1 = e1/20, rx1 = e1%20;
  int y0 = i0 - 2 + ry0, x0 = j0 + rx0;
  int y1 = i0 - 2 + ry1, x1 = j0 + rx1;
  bool v0 = (y0 >= 0 && y0 < 64 && x0 < 64);
  bool v1 = (e1 < 400) && (y1 >= 0 && y1 < 64 && x1 < 64);
  const float* p0 = xib + (v0 ? ((size_t)y0*64 + x0) : 0);
  const float* p1 = xib + (v1 ? ((size_t)y1*64 + x1) : 0);

  float pf0 = v0 ? p0[0] : 0.f;
  float pf1 = v1 ? p1[0] : 0.f;

  for (int c = 0; c < NC; ++c) {
    __syncthreads();                       // all readers of s done
    s[ry0][rx0] = pf0;
    if (e1 < 400) s[ry1][rx1] = pf1;
    __syncthreads();                       // s ready
    if (c + 1 < NC) {                      // issue next channel loads early
      pf0 = v0 ? p0[(size_t)(c+1)*NN] : 0.f;
      pf1 = v1 ? p1[(size_t)(c+1)*NN] : 0.f;
    }
    float iv[25];
#pragma unroll
    for (int dy = 0; dy < 5; ++dy)
#pragma unroll
      for (int dx = 0; dx < 5; ++dx)
        iv[dy*5+dx] = s[ty+dy][tx+dx];
    const float* wc = wp + c*25;
#pragma unroll
    for (int o = 0; o < 25; ++o) {
      const float* wo = wc + (size_t)o*1250;   // wave-uniform -> s_load
      float a = acc[o];
#pragma unroll
      for (int k = 0; k < 25; ++k) a += iv[k]*wo[k];
      acc[o] = a;
    }
  }

  int i = i0 + ty, j = j0 + tx;
  if (i < 62 && j < 62) {
#pragma unroll
    for (int o = 0; o < 25; ++o) {
      int oc = o0 + o;
      float sc = g[p*NC+oc] * rsqrtf(va[p*NC+oc] + 1e-5f);
      float sh = be[p*NC+oc] - mu[p*NC+oc]*sc;
      t1[((size_t)(p*NB+b)*NC + oc)*3844 + i*62 + j] = acc[o]*sc + sh;
    }
  }
}

// ---------------- K2: conv2 2x2 (pad top3/right3) -> qkv f32 + q/k bf16 ----------------
__global__ __launch_bounds__(256) void k_conv2(const float* __restrict__ t1,
                                               const float* __restrict__ w2,
                                               float* __restrict__ qkv,
                                               __hip_bfloat16* __restrict__ qb,
                                               __hip_bfloat16* __restrict__ kb) {
  __shared__ float s[17][20];
  int tile = blockIdx.x;
  int h0 = (tile >> 2) * 16, w0 = (tile & 3) * 16;
  int pb = blockIdx.y; int p = pb >> 2, b = pb & 3;
  int og = blockIdx.z, o0 = og * 25;
  int tx = threadIdx.x & 15, ty = threadIdx.x >> 4;

  const float* tb = t1 + (size_t)(p*NB+b)*NC*3844;
  const float* wp = w2 + (size_t)p*10000 + (size_t)o0*200;   // [o][c][4]

  float acc[25];
#pragma unroll
  for (int o = 0; o < 25; ++o) acc[o] = 0.f;

  int e0 = threadIdx.x, e1 = threadIdx.x + 256;   // 289 elems
  int ry0 = e0/17, rx0 = e0%17, ry1 = e1/17, rx1 = e1%17;
  int y0 = h0 - 3 + ry0, x0 = w0 + rx0;
  int y1 = h0 - 3 + ry1, x1 = w0 + rx1;
  bool v0 = (y0 >= 0 && y0 < 62 && x0 < 62);
  bool v1 = (e1 < 289) && (y1 >= 0 && y1 < 62 && x1 < 62);
  const float* p0 = tb + (v0 ? ((size_t)y0*62 + x0) : 0);
  const float* p1 = tb + (v1 ? ((size_t)y1*62 + x1) : 0);

  float pf0 = v0 ? p0[0] : 0.f;
  float pf1 = v1 ? p1[0] : 0.f;

  for (int c = 0; c < NC; ++c) {
    __syncthreads();
    s[ry0][rx0] = pf0;
    if (e1 < 289) s[ry1][rx1] = pf1;
    __syncthreads();
    if (c + 1 < NC) {
      pf0 = v0 ? p0[(size_t)(c+1)*3844] : 0.f;
      pf1 = v1 ? p1[(size_t)(c+1)*3844] : 0.f;
    }
    float i00 = s[ty][tx],   i01 = s[ty][tx+1];
    float i10 = s[ty+1][tx], i11 = s[ty+1][tx+1];
    const float* wc = wp + c*4;
#pragma unroll
    for (int o = 0; o < 25; ++o) {
      const float* wo = wc + (size_t)o*200;    // wave-uniform -> s_load
      acc[o] += i00*wo[0] + i01*wo[1] + i10*wo[2] + i11*wo[3];
    }
  }

  int n = (h0 + ty)*64 + (w0 + tx);
  float* dst = qkv + ((size_t)(p*NB+b)*NN + n)*QS;
#pragma unroll
  for (int o = 0; o < 25; ++o) dst[o0+o] = acc[o];
  if (og == 1) { dst[50] = 0.f; dst[51] = 0.f; }

  if (p == 0) {
    __hip_bfloat16* qr = qb + ((size_t)b*NN + n)*64;
#pragma unroll
    for (int o = 0; o < 25; ++o) qr[o0+o] = __float2bfloat16(acc[o]*F_SCALE);
    if (og == 1) for (int z = 50; z < 64; ++z) qr[z] = __float2bfloat16(0.f);
  } else if (p == 1) {
    __hip_bfloat16* kr = kb + ((size_t)b*NN + n)*64;
#pragma unroll
    for (int o = 0; o < 25; ++o) kr[o0+o] = __float2bfloat16(acc[o]);
    if (og == 1) for (int z = 50; z < 64; ++z) kr[z] = __float2bfloat16(0.f);
  }
}

// ---------------- K3: MFMA row sums  L_t = sum_j exp(q_t . k_j) ----------------
// grid (64 t-tiles, 4 j-chunks, B), block 256 (4 waves x 16 rows)
__global__ __launch_bounds__(256) void k_L(const __hip_bfloat16* __restrict__ qb,
                                           const __hip_bfloat16* __restrict__ kb,
                                           float* __restrict__ Lpart) {
  int w = threadIdx.x >> 6, lane = threadIdx.x & 63;
  int b = blockIdx.z, jc = blockIdx.y;
  int t0 = blockIdx.x * 64 + w * 16;
  int lr = lane & 15, lk = lane >> 4;

  const short* qrow = (const short*)qb + ((size_t)b*NN + t0 + lr)*64 + lk*8;
  short8 a0 = *(const short8*)qrow;
  short8 a1 = *(const short8*)(qrow + 32);
  const short* kbase = (const short*)kb + (size_t)b*NN*64;

  float rs[4] = {0.f, 0.f, 0.f, 0.f};
  for (int j = jc*1024; j < jc*1024 + 1024; j += 16) {
    const short* krow = kbase + (size_t)(j + lr)*64 + lk*8;
    short8 b0 = *(const short8*)krow;
    short8 b1 = *(const short8*)(krow + 32);
    f32x4 d = {0.f, 0.f, 0.f, 0.f};
    d = __builtin_amdgcn_mfma_f32_16x16x32_bf16(a0, b0, d, 0, 0, 0);
    d = __builtin_amdgcn_mfma_f32_16x16x32_bf16(a1, b1, d, 0, 0, 0);
#pragma unroll
    for (int r = 0; r < 4; ++r) rs[r] += __expf(d[r]);   // scale folded into qb
  }
#pragma unroll
  for (int r = 0; r < 4; ++r) {
#pragma unroll
    for (int m = 1; m < 16; m <<= 1) rs[r] += __shfl_xor(rs[r], m, 64);
  }
  if (lr == 0) {
    size_t base = (size_t)jc*(NB*NN) + (size_t)b*NN + t0 + lk*4;
#pragma unroll
    for (int r = 0; r < 4; ++r) Lpart[base + r] = rs[r];
  }
}

__global__ __launch_bounds__(256) void k_Lred(const float* __restrict__ Lpart,
                                              float* __restrict__ L,
                                              float* __restrict__ Linv) {
  int i = blockIdx.x * 256 + threadIdx.x;   // 16384
  float sum = 0.f;
#pragma unroll
  for (int jc = 0; jc < 4; ++jc) sum += Lpart[(size_t)jc*(NB*NN) + i];
  L[i] = sum;
  Linv[i] = 1.f / sum;
}

// ---------------- K4: MFMA column totals  Ctot_j = sum_t exp(.)/L_t ----------------
// grid (64 j-tiles, 4 t-chunks, B), block 256 (4 waves x 16 cols)
__global__ __launch_bounds__(256) void k_Ctot(const __hip_bfloat16* __restrict__ qb,
                                              const __hip_bfloat16* __restrict__ kb,
                                              const float* __restrict__ Linv,
                                              float* __restrict__ Cpart) {
  int w = threadIdx.x >> 6, lane = threadIdx.x & 63;
  int b = blockIdx.z, tc = blockIdx.y;
  int j0 = blockIdx.x * 64 + w * 16;
  int lr = lane & 15, lk = lane >> 4;

  const short* krow = (const short*)kb + ((size_t)b*NN + j0 + lr)*64 + lk*8;
  short8 b0 = *(const short8*)krow;
  short8 b1 = *(const short8*)(krow + 32);
  const short* qbase = (const short*)qb + (size_t)b*NN*64;
  const float* Li = Linv + (size_t)b*NN;

  float cacc = 0.f;
  for (int t = tc*1024; t < tc*1024 + 1024; t += 16) {
    const short* qrow = qbase + (size_t)(t + lr)*64 + lk*8;
    short8 a0 = *(const short8*)qrow;
    short8 a1 = *(const short8*)(qrow + 32);
    f32x4 d = {0.f, 0.f, 0.f, 0.f};
    d = __builtin_amdgcn_mfma_f32_16x16x32_bf16(a0, b0, d, 0, 0, 0);
    d = __builtin_amdgcn_mfma_f32_16x16x32_bf16(a1, b1, d, 0, 0, 0);
    int r0 = t + lk*4;
    cacc += __expf(d[0])*Li[r0]   + __expf(d[1])*Li[r0+1]
          + __expf(d[2])*Li[r0+2] + __expf(d[3])*Li[r0+3];
  }
  cacc += __shfl_xor(cacc, 16, 64);
  cacc += __shfl_xor(cacc, 32, 64);
  if (lane < 16) Cpart[(size_t)tc*(NB*NN) + (size_t)b*NN + j0 + lane] = cacc;
}

__global__ __launch_bounds__(256) void k_Cred(const float* __restrict__ Cpart,
                                              float* __restrict__ Ctot) {
  int i = blockIdx.x * 256 + threadIdx.x;
  float sum = 0.f;
#pragma unroll
  for (int tc = 0; tc < 4; ++tc) sum += Cpart[(size_t)tc*(NB*NN) + i];
  Ctot[i] = sum;
}

__global__ __launch_bounds__(1024) void k_zero(float* __restrict__ out) {
  size_t i = (size_t)blockIdx.x * 1024 + threadIdx.x;
  if (i < (size_t)NB*NN*NC) out[i] = 0.f;
}

// ---------------- K5: spike fallback (exact serial walk, only for flagged cols) ----
// A column can spike only if its monotone cumulative dt*Ctot crosses an integer;
// dt*Ctot ~ 1e-3 here so every thread early-exits. Keeps general correctness.
__global__ __launch_bounds__(256) void k_spike_fb(const float* __restrict__ qkv,
                                                  const float* __restrict__ L,
                                                  const float* __restrict__ Ctot,
                                                  float* __restrict__ out) {
  int j = blockIdx.x * 256 + threadIdx.x;
  int b = blockIdx.y;
  if (F_DT * Ctot[(size_t)b*NN + j] < 0.5f) return;

  float kreg[52];
  load52(kreg, (const float4*)(qkv + ((size_t)NB*NN + (size_t)b*NN + j)*QS));
  const float* Qb = qkv + (size_t)b*NN*QS;
  const float* Lb = L + (size_t)b*NN;
  const float* V  = qkv + ((size_t)2*NB*NN + (size_t)b*NN + j)*QS;

  float cum = 0.f, Fprev = 0.f;
  for (int t = 0; t < NN; ++t) {
    float dot = dot52(kreg, (const float4*)(Qb + (size_t)t*QS));
    float r = __expf(dot * F_SCALE) / Lb[t];
    cum += r * F_DT;
    float F = floorf(cum);
    if (F > Fprev) {
      float sv = (F - Fprev) / F_DT;
      float* orow = out + ((size_t)b*NN + t)*NC;
      for (int d = 0; d < NC; ++d) atomicAdd(orow + d, sv * V[d]);
      Fprev = F;
    }
  }
}

extern "C" void kernel_launch(void* const* d_in, const int* in_sizes, int n_in,
                              void* d_out, int out_size, void* d_ws, size_t ws_size,
                              hipStream_t stream) {
  const float* x  = (const float*)d_in[0];
  const float* w1 = (const float*)d_in[1];
  const float* w2 = (const float*)d_in[2];
  const float* g  = (const float*)d_in[3];
  const float* be = (const float*)d_in[4];
  const float* mu = (const float*)d_in[5];
  const float* va = (const float*)d_in[6];
  float* out = (float*)d_out;
  float* ws  = (float*)d_ws;

  float* xi   = ws + OFF_XI;
  float* t1   = ws + OFF_T1;
  float* qkv  = ws + OFF_QKV;
  __hip_bfloat16* qb = (__hip_bfloat16*)(ws + OFF_QB);
  __hip_bfloat16* kb = (__hip_bfloat16*)(ws + OFF_KB);
  float* Lp   = ws + OFF_LP;
  float* L    = ws + OFF_L;
  float* Li   = ws + OFF_LI;
  float* Cp   = ws + OFF_CP;
  float* Ct   = ws + OFF_CT;

  k_transpose<<<dim3(256), dim3(256), 0, stream>>>(x, xi);
  k_conv1<<<dim3(16, 12, 2), dim3(256), 0, stream>>>(xi, w1, g, be, mu, va, t1);
  k_conv2<<<dim3(16, 12, 2), dim3(256), 0, stream>>>(t1, w2, qkv, qb, kb);
  k_L<<<dim3(64, 4, NB), dim3(256), 0, stream>>>(qb, kb, Lp);
  k_Lred<<<dim3(64), dim3(256), 0, stream>>>(Lp, L, Li);
  k_Ctot<<<dim3(64, 4, NB), dim3(256), 0, stream>>>(qb, kb, Li, Cp);
  k_Cred<<<dim3(64), dim3(256), 0, stream>>>(Cp, Ct);
  k_zero<<<dim3(800), dim3(1024), 0, stream>>>(out);
  k_spike_fb<<<dim3(16, NB), dim3(256), 0, stream>>>(qkv, L, Ct, out);
}

// Round 3
// 252.525 us; speedup vs baseline: 3.9097x; 2.1880x over previous
//
#include <hip/hip_runtime.h>
#include <hip/hip_bf16.h>
#include <math.h>

#define NB 4
#define NC 50
#define NN 4096

typedef __attribute__((ext_vector_type(8))) short short8;
typedef __attribute__((ext_vector_type(4))) float f32x4;

static constexpr float F_SCALE = 0.14142135623730951f; // 50^-0.5 (folded into qb)
static constexpr float F_DT = 0.001f;

// ---- workspace layout (f32 units) ----
static constexpr size_t OFF_XP  = 0;                                   // xpad [4][66][68][64] bf16
static constexpr size_t SZ_XP   = (size_t)4*66*68*64/2;                // 574464
static constexpr size_t OFF_W1T = OFF_XP + SZ_XP;                      // w1t [3][25][64][64] bf16
static constexpr size_t SZ_W1T  = (size_t)3*25*64*64/2;                // 153600
static constexpr size_t OFF_BI  = OFF_W1T + SZ_W1T;                    // bias [3][64] f32
static constexpr size_t SZ_BI   = 192;
static constexpr size_t OFF_W2T = OFF_BI + SZ_BI;                      // w2t [3][4][64][64] bf16
static constexpr size_t SZ_W2T  = (size_t)3*4*64*64/2;                 // 24576
static constexpr size_t OFF_T1P = OFF_W2T + SZ_W2T;                    // t1pad [12][66][66][64] bf16
static constexpr size_t SZ_T1P  = (size_t)12*66*66*64/2;               // 1672704
static constexpr size_t OFF_QB  = OFF_T1P + SZ_T1P;                    // qb [4][4096][64] bf16
static constexpr size_t SZ_QB   = (size_t)4*NN*64/2;                   // 524288
static constexpr size_t OFF_KB  = OFF_QB + SZ_QB;
static constexpr size_t SZ_KB   = SZ_QB;
static constexpr size_t OFF_VV  = OFF_KB + SZ_KB;                      // vv [4][4096][64] f32
static constexpr size_t SZ_VV   = (size_t)4*NN*64;
static constexpr size_t OFF_LP  = OFF_VV + SZ_VV;                      // [4][16384]
static constexpr size_t SZ_LP   = (size_t)4*NB*NN;
static constexpr size_t OFF_L   = OFF_LP + SZ_LP;                      // [16384]
static constexpr size_t SZ_L    = (size_t)NB*NN;
static constexpr size_t OFF_LI  = OFF_L + SZ_L;
static constexpr size_t SZ_LI   = SZ_L;
static constexpr size_t OFF_CP  = OFF_LI + SZ_LI;                      // [4][16384]
static constexpr size_t SZ_CP   = (size_t)4*NB*NN;
static constexpr size_t OFF_CT  = OFF_CP + SZ_CP;                      // [16384]
// end ~18.8 MB

// ---------------- P0: build padded bf16 image xpad[b][66][68][64] ----------------
// xpad[b][h][w][c] = x[b][(h-2)*64+w][c] when valid else 0 (pads: top2, right, ch)
__global__ __launch_bounds__(256) void k_xprep(const float* __restrict__ x,
                                               __hip_bfloat16* __restrict__ xp) {
  int t = threadIdx.x;
  int pos = blockIdx.x * 4 + (t >> 6);
  int c = t & 63;
  int b = pos / 4488;            // 66*68
  int rem = pos % 4488;
  int h = rem / 68, w = rem % 68;
  int y = h - 2;
  float v = 0.f;
  if (y >= 0 && y < 64 && w < 64 && c < NC)
    v = x[((size_t)b*NN + y*64 + w)*NC + c];
  xp[(size_t)pos*64 + c] = __float2bfloat16(v);
}

// ---------------- P1: weight transpose (+BN fold for conv1) ----------------
// blocks 0..74: w1t[p][tap][oc][c] = w1[p][oc][c][tap]*sc[p][oc]; bias when tap==0
// blocks 75..86: w2t[p][tap][oc][c] = w2[p][oc][c][tap]
__global__ __launch_bounds__(256) void k_wprep(const float* __restrict__ w1,
                                               const float* __restrict__ w2,
                                               const float* __restrict__ g,
                                               const float* __restrict__ be,
                                               const float* __restrict__ mu,
                                               const float* __restrict__ va,
                                               __hip_bfloat16* __restrict__ w1t,
                                               float* __restrict__ bias,
                                               __hip_bfloat16* __restrict__ w2t) {
  int bx = blockIdx.x;
  if (bx < 75) {
    int p = bx / 25, tap = bx % 25;
    for (int i = threadIdx.x; i < 4096; i += 256) {
      int oc = i >> 6, c = i & 63;
      float v = 0.f;
      if (oc < NC && c < NC) {
        float sc = g[p*NC+oc] * rsqrtf(va[p*NC+oc] + 1e-5f);
        v = w1[(((size_t)p*NC + oc)*NC + c)*25 + tap] * sc;
      }
      w1t[(((size_t)p*25 + tap)*64 + oc)*64 + c] = __float2bfloat16(v);
    }
    if (tap == 0 && threadIdx.x < 64) {
      int oc = threadIdx.x;
      float v = 0.f;
      if (oc < NC) {
        float sc = g[p*NC+oc] * rsqrtf(va[p*NC+oc] + 1e-5f);
        v = be[p*NC+oc] - mu[p*NC+oc]*sc;
      }
      bias[p*64 + oc] = v;
    }
  } else {
    int i2 = bx - 75;
    int p = i2 / 4, tap = i2 % 4;
    for (int i = threadIdx.x; i < 4096; i += 256) {
      int oc = i >> 6, c = i & 63;
      float v = 0.f;
      if (oc < NC && c < NC)
        v = w2[(((size_t)p*NC + oc)*NC + c)*4 + tap];
      w2t[(((size_t)p*4 + tap)*64 + oc)*64 + c] = __float2bfloat16(v);
    }
  }
}

// ---------------- P2: zero t1pad pad strips (ws is poisoned, not re-zeroed) --------
// per (p,b): rows {0,1,2,65} full + rows[3..64] cols{62..65} = 32768 bf16
__global__ __launch_bounds__(256) void k_zstrip(__hip_bfloat16* __restrict__ t1p) {
  int idx = blockIdx.x * 256 + threadIdx.x;   // < 12*32768
  int pb = idx >> 15, r = idx & 32767;
  int h2, w, c;
  if (r < 16896) {
    int hsel = r / 4224;          // 66*64
    h2 = hsel < 3 ? hsel : 65;
    int rem = r % 4224;
    w = rem >> 6; c = rem & 63;
  } else {
    int r2 = r - 16896;
    h2 = 3 + (r2 >> 8);
    int rem = r2 & 255;
    w = 62 + (rem >> 6); c = rem & 63;
  }
  t1p[(((size_t)pb*66 + h2)*66 + w)*64 + c] = __float2bfloat16(0.f);
}

__global__ __launch_bounds__(1024) void k_zero(float* __restrict__ out) {
  size_t i = (size_t)blockIdx.x * 1024 + threadIdx.x;
  if (i < (size_t)NB*NN*NC) out[i] = 0.f;
}

// ---------------- C1: conv1 5x5 as 25-tap shift-GEMM (MFMA) + BN -> t1pad bf16 -----
// grid (62 rows, 12 p*b), block 256 = 4 waves; wave jt covers output cols jt*16..+15
__global__ __launch_bounds__(256) void k_conv1m(const __hip_bfloat16* __restrict__ xp,
                                                const __hip_bfloat16* __restrict__ w1t,
                                                const float* __restrict__ bias,
                                                __hip_bfloat16* __restrict__ t1p) {
  int jt = threadIdx.x >> 6, lane = threadIdx.x & 63;
  int lr = lane & 15, lk = lane >> 4;
  int i1 = blockIdx.x;
  int pb = blockIdx.y; int p = pb / 4, b = pb % 4;

  const short* xa = (const short*)xp
      + (((size_t)b*66 + i1)*68 + jt*16 + lr)*64 + lk*8;       // A row j1=jt*16+lr
  const short* wb = (const short*)w1t
      + ((size_t)p*25*64 + lr)*64 + lk*8;                      // B row oc=nt*16+lr

  f32x4 acc[4];
#pragma unroll
  for (int nt = 0; nt < 4; ++nt) acc[nt] = (f32x4){0.f,0.f,0.f,0.f};

  for (int tap = 0; tap < 25; ++tap) {
    int dy = tap / 5, dx = tap % 5;
    const short* ar = xa + ((size_t)dy*68 + dx)*64;
    short8 a0 = *(const short8*)ar;
    short8 a1 = *(const short8*)(ar + 32);
    const short* wr = wb + (size_t)tap*4096;
#pragma unroll
    for (int nt = 0; nt < 4; ++nt) {
      short8 b0 = *(const short8*)(wr + nt*1024);
      short8 b1 = *(const short8*)(wr + nt*1024 + 32);
      acc[nt] = __builtin_amdgcn_mfma_f32_16x16x32_bf16(a0, b0, acc[nt], 0, 0, 0);
      acc[nt] = __builtin_amdgcn_mfma_f32_16x16x32_bf16(a1, b1, acc[nt], 0, 0, 0);
    }
  }

  // D: col = lane&15 (oc_local), row = lk*4 + r (pixel within 16-col tile)
  int h2 = i1 + 3;
  __hip_bfloat16* orow = t1p + (((size_t)(p*NB + b)*66 + h2)*66)*64;
#pragma unroll
  for (int nt = 0; nt < 4; ++nt) {
    float bv = bias[p*64 + nt*16 + lr];
#pragma unroll
    for (int r = 0; r < 4; ++r) {
      int j1 = jt*16 + lk*4 + r;
      float val = (j1 < 62) ? (acc[nt][r] + bv) : 0.f;         // cols 62,63 = pad
      orow[(size_t)j1*64 + nt*16 + lr] = __float2bfloat16(val);
    }
  }
}

// ---------------- C2: conv2 2x2 as 4-tap shift-GEMM (MFMA) -> qb/kb bf16, vv f32 ---
// grid (64 rows, 12 p*b), block 256 = 4 waves
__global__ __launch_bounds__(256) void k_conv2m(const __hip_bfloat16* __restrict__ t1p,
                                                const __hip_bfloat16* __restrict__ w2t,
                                                __hip_bfloat16* __restrict__ qb,
                                                __hip_bfloat16* __restrict__ kb,
                                                float* __restrict__ vv) {
  int jt = threadIdx.x >> 6, lane = threadIdx.x & 63;
  int lr = lane & 15, lk = lane >> 4;
  int i2 = blockIdx.x;
  int pb = blockIdx.y; int p = pb / 4, b = pb % 4;

  const short* xa = (const short*)t1p
      + (((size_t)(p*NB + b)*66 + i2)*66 + jt*16 + lr)*64 + lk*8;
  const short* wb = (const short*)w2t
      + ((size_t)p*4*64 + lr)*64 + lk*8;

  f32x4 acc[4];
#pragma unroll
  for (int nt = 0; nt < 4; ++nt) acc[nt] = (f32x4){0.f,0.f,0.f,0.f};

#pragma unroll
  for (int tap = 0; tap < 4; ++tap) {
    int dy = tap >> 1, dx = tap & 1;
    const short* ar = xa + ((size_t)dy*66 + dx)*64;
    short8 a0 = *(const short8*)ar;
    short8 a1 = *(const short8*)(ar + 32);
    const short* wr = wb + (size_t)tap*4096;
#pragma unroll
    for (int nt = 0; nt < 4; ++nt) {
      short8 b0 = *(const short8*)(wr + nt*1024);
      short8 b1 = *(const short8*)(wr + nt*1024 + 32);
      acc[nt] = __builtin_amdgcn_mfma_f32_16x16x32_bf16(a0, b0, acc[nt], 0, 0, 0);
      acc[nt] = __builtin_amdgcn_mfma_f32_16x16x32_bf16(a1, b1, acc[nt], 0, 0, 0);
    }
  }

#pragma unroll
  for (int nt = 0; nt < 4; ++nt) {
#pragma unroll
    for (int r = 0; r < 4; ++r) {
      int n = i2*64 + jt*16 + lk*4 + r;
      int oc = nt*16 + lr;
      float val = acc[nt][r];
      if (p == 0) {
        qb[((size_t)b*NN + n)*64 + oc] = __float2bfloat16(val * F_SCALE);
      } else if (p == 1) {
        kb[((size_t)b*NN + n)*64 + oc] = __float2bfloat16(val);
      } else {
        vv[((size_t)b*NN + n)*64 + oc] = val;
      }
    }
  }
}

// ---------------- K3: MFMA row sums  L_t = sum_j exp(q_t . k_j) ----------------
__global__ __launch_bounds__(256) void k_L(const __hip_bfloat16* __restrict__ qb,
                                           const __hip_bfloat16* __restrict__ kb,
                                           float* __restrict__ Lpart) {
  int w = threadIdx.x >> 6, lane = threadIdx.x & 63;
  int b = blockIdx.z, jc = blockIdx.y;
  int t0 = blockIdx.x * 64 + w * 16;
  int lr = lane & 15, lk = lane >> 4;

  const short* qrow = (const short*)qb + ((size_t)b*NN + t0 + lr)*64 + lk*8;
  short8 a0 = *(const short8*)qrow;
  short8 a1 = *(const short8*)(qrow + 32);
  const short* kbase = (const short*)kb + (size_t)b*NN*64;

  float rs[4] = {0.f, 0.f, 0.f, 0.f};
#pragma unroll 4
  for (int j = jc*1024; j < jc*1024 + 1024; j += 16) {
    const short* krow = kbase + (size_t)(j + lr)*64 + lk*8;
    short8 b0 = *(const short8*)krow;
    short8 b1 = *(const short8*)(krow + 32);
    f32x4 d = {0.f, 0.f, 0.f, 0.f};
    d = __builtin_amdgcn_mfma_f32_16x16x32_bf16(a0, b0, d, 0, 0, 0);
    d = __builtin_amdgcn_mfma_f32_16x16x32_bf16(a1, b1, d, 0, 0, 0);
#pragma unroll
    for (int r = 0; r < 4; ++r) rs[r] += __expf(d[r]);
  }
#pragma unroll
  for (int r = 0; r < 4; ++r) {
#pragma unroll
    for (int m = 1; m < 16; m <<= 1) rs[r] += __shfl_xor(rs[r], m, 64);
  }
  if (lr == 0) {
    size_t base = (size_t)jc*(NB*NN) + (size_t)b*NN + t0 + lk*4;
#pragma unroll
    for (int r = 0; r < 4; ++r) Lpart[base + r] = rs[r];
  }
}

__global__ __launch_bounds__(256) void k_Lred(const float* __restrict__ Lpart,
                                              float* __restrict__ L,
                                              float* __restrict__ Linv) {
  int i = blockIdx.x * 256 + threadIdx.x;
  float sum = 0.f;
#pragma unroll
  for (int jc = 0; jc < 4; ++jc) sum += Lpart[(size_t)jc*(NB*NN) + i];
  L[i] = sum;
  Linv[i] = 1.f / sum;
}

// ---------------- K4: MFMA column totals  Ctot_j = sum_t exp(.)/L_t ----------------
__global__ __launch_bounds__(256) void k_Ctot(const __hip_bfloat16* __restrict__ qb,
                                              const __hip_bfloat16* __restrict__ kb,
                                              const float* __restrict__ Linv,
                                              float* __restrict__ Cpart) {
  int w = threadIdx.x >> 6, lane = threadIdx.x & 63;
  int b = blockIdx.z, tc = blockIdx.y;
  int j0 = blockIdx.x * 64 + w * 16;
  int lr = lane & 15, lk = lane >> 4;

  const short* krow = (const short*)kb + ((size_t)b*NN + j0 + lr)*64 + lk*8;
  short8 b0 = *(const short8*)krow;
  short8 b1 = *(const short8*)(krow + 32);
  const short* qbase = (const short*)qb + (size_t)b*NN*64;
  const float* Li = Linv + (size_t)b*NN;

  float cacc = 0.f;
#pragma unroll 4
  for (int t = tc*1024; t < tc*1024 + 1024; t += 16) {
    const short* qrow = qbase + (size_t)(t + lr)*64 + lk*8;
    short8 a0 = *(const short8*)qrow;
    short8 a1 = *(const short8*)(qrow + 32);
    f32x4 d = {0.f, 0.f, 0.f, 0.f};
    d = __builtin_amdgcn_mfma_f32_16x16x32_bf16(a0, b0, d, 0, 0, 0);
    d = __builtin_amdgcn_mfma_f32_16x16x32_bf16(a1, b1, d, 0, 0, 0);
    int r0 = t + lk*4;
    cacc += __expf(d[0])*Li[r0]   + __expf(d[1])*Li[r0+1]
          + __expf(d[2])*Li[r0+2] + __expf(d[3])*Li[r0+3];
  }
  cacc += __shfl_xor(cacc, 16, 64);
  cacc += __shfl_xor(cacc, 32, 64);
  if (lane < 16) Cpart[(size_t)tc*(NB*NN) + (size_t)b*NN + j0 + lane] = cacc;
}

__global__ __launch_bounds__(256) void k_Cred(const float* __restrict__ Cpart,
                                              float* __restrict__ Ctot) {
  int i = blockIdx.x * 256 + threadIdx.x;
  float sum = 0.f;
#pragma unroll
  for (int tc = 0; tc < 4; ++tc) sum += Cpart[(size_t)tc*(NB*NN) + i];
  Ctot[i] = sum;
}

// ---------------- K5: spike fallback (exact serial walk, gated by column bound) ----
// monotone cum v: spikes possible only if dt*Ctot_j crosses an integer; here ~1e-3.
__global__ __launch_bounds__(256) void k_spike_fb(const __hip_bfloat16* __restrict__ qb,
                                                  const __hip_bfloat16* __restrict__ kb,
                                                  const float* __restrict__ L,
                                                  const float* __restrict__ Ctot,
                                                  const float* __restrict__ vv,
                                                  float* __restrict__ out) {
  int j = blockIdx.x * 256 + threadIdx.x;
  int b = blockIdx.y;
  if (F_DT * Ctot[(size_t)b*NN + j] < 0.5f) return;

  float kf[64];
  const __hip_bfloat16* kr = kb + ((size_t)b*NN + j)*64;
#pragma unroll
  for (int c = 0; c < 64; ++c) kf[c] = __bfloat162float(kr[c]);
  const __hip_bfloat16* Qb = qb + (size_t)b*NN*64;
  const float* Lb = L + (size_t)b*NN;
  const float* V  = vv + ((size_t)b*NN + j)*64;

  float cum = 0.f, Fprev = 0.f;
  for (int t = 0; t < NN; ++t) {
    const __hip_bfloat16* qr = Qb + (size_t)t*64;
    float dot = 0.f;
    for (int c = 0; c < 64; ++c) dot += __bfloat162float(qr[c]) * kf[c];
    float r = __expf(dot) / Lb[t];
    cum += r * F_DT;
    float F = floorf(cum);
    if (F > Fprev) {
      float sv = (F - Fprev) / F_DT;
      float* orow = out + ((size_t)b*NN + t)*NC;
      for (int d = 0; d < NC; ++d) atomicAdd(orow + d, sv * V[d]);
      Fprev = F;
    }
  }
}

extern "C" void kernel_launch(void* const* d_in, const int* in_sizes, int n_in,
                              void* d_out, int out_size, void* d_ws, size_t ws_size,
                              hipStream_t stream) {
  const float* x  = (const float*)d_in[0];
  const float* w1 = (const float*)d_in[1];
  const float* w2 = (const float*)d_in[2];
  const float* g  = (const float*)d_in[3];
  const float* be = (const float*)d_in[4];
  const float* mu = (const float*)d_in[5];
  const float* va = (const float*)d_in[6];
  float* out = (float*)d_out;
  float* ws  = (float*)d_ws;

  __hip_bfloat16* xp  = (__hip_bfloat16*)(ws + OFF_XP);
  __hip_bfloat16* w1t = (__hip_bfloat16*)(ws + OFF_W1T);
  float*          bi  = ws + OFF_BI;
  __hip_bfloat16* w2t = (__hip_bfloat16*)(ws + OFF_W2T);
  __hip_bfloat16* t1p = (__hip_bfloat16*)(ws + OFF_T1P);
  __hip_bfloat16* qb  = (__hip_bfloat16*)(ws + OFF_QB);
  __hip_bfloat16* kb  = (__hip_bfloat16*)(ws + OFF_KB);
  float* vv = ws + OFF_VV;
  float* Lp = ws + OFF_LP;
  float* L  = ws + OFF_L;
  float* Li = ws + OFF_LI;
  float* Cp = ws + OFF_CP;
  float* Ct = ws + OFF_CT;

  k_xprep <<<dim3(4488), dim3(256), 0, stream>>>(x, xp);
  k_wprep <<<dim3(87),   dim3(256), 0, stream>>>(w1, w2, g, be, mu, va, w1t, bi, w2t);
  k_zstrip<<<dim3(1536), dim3(256), 0, stream>>>(t1p);
  k_zero  <<<dim3(800),  dim3(1024), 0, stream>>>(out);
  k_conv1m<<<dim3(62, 12), dim3(256), 0, stream>>>(xp, w1t, bi, t1p);
  k_conv2m<<<dim3(64, 12), dim3(256), 0, stream>>>(t1p, w2t, qb, kb, vv);
  k_L     <<<dim3(64, 4, NB), dim3(256), 0, stream>>>(qb, kb, Lp);
  k_Lred  <<<dim3(64), dim3(256), 0, stream>>>(Lp, L, Li);
  k_Ctot  <<<dim3(64, 4, NB), dim3(256), 0, stream>>>(qb, kb, Li, Cp);
  k_Cred  <<<dim3(64), dim3(256), 0, stream>>>(Cp, Ct);
  k_spike_fb<<<dim3(16, NB), dim3(256), 0, stream>>>(qb, kb, L, Ct, vv, out);
}

// Round 4
// 209.547 us; speedup vs baseline: 4.7116x; 1.2051x over previous
//
#include <hip/hip_runtime.h>
#include <hip/hip_bf16.h>
#include <math.h>

#define NB 4
#define NC 50
#define NN 4096

typedef __attribute__((ext_vector_type(8))) short short8;
typedef __attribute__((ext_vector_type(4))) float f32x4;

static constexpr float F_SCALE = 0.14142135623730951f;  // 50^-0.5
static constexpr float F_LOG2E = 1.44269504088896340f;  // fold into qb: exp(x)=exp2(x*log2e)
static constexpr float F_DT = 0.001f;

// ---- workspace layout (f32 units) ----
static constexpr size_t OFF_XP  = 0;                                   // xpad [4][66][68][64] bf16
static constexpr size_t SZ_XP   = (size_t)4*66*68*64/2;
static constexpr size_t OFF_W1T = OFF_XP + SZ_XP;                      // w1t2 [3][50ks][64oc][32] bf16
static constexpr size_t SZ_W1T  = (size_t)3*25*64*64/2;
static constexpr size_t OFF_BI  = OFF_W1T + SZ_W1T;                    // bias [3][64] f32
static constexpr size_t SZ_BI   = 192;
static constexpr size_t OFF_W2T = OFF_BI + SZ_BI;                      // w2t2 [3][8ks][64oc][32] bf16
static constexpr size_t SZ_W2T  = (size_t)3*4*64*64/2;
static constexpr size_t OFF_T1P = OFF_W2T + SZ_W2T;                    // t1pad [12][66][66][64] bf16
static constexpr size_t SZ_T1P  = (size_t)12*66*66*64/2;
static constexpr size_t OFF_QB  = OFF_T1P + SZ_T1P;                    // qb [4][4096][64] bf16 (scaled*log2e)
static constexpr size_t SZ_QB   = (size_t)4*NN*64/2;
static constexpr size_t OFF_KB  = OFF_QB + SZ_QB;
static constexpr size_t SZ_KB   = SZ_QB;
static constexpr size_t OFF_VV  = OFF_KB + SZ_KB;                      // vv [4][4096][64] f32
static constexpr size_t SZ_VV   = (size_t)4*NN*64;
static constexpr size_t OFF_LP  = OFF_VV + SZ_VV;                      // [4][16384]
static constexpr size_t SZ_LP   = (size_t)4*NB*NN;
static constexpr size_t OFF_L   = OFF_LP + SZ_LP;                      // [16384]
static constexpr size_t SZ_L    = (size_t)NB*NN;
static constexpr size_t OFF_LI  = OFF_L + SZ_L;
static constexpr size_t SZ_LI   = SZ_L;
static constexpr size_t OFF_CP  = OFF_LI + SZ_LI;                      // [4][16384]
static constexpr size_t SZ_CP   = (size_t)4*NB*NN;
static constexpr size_t OFF_CT  = OFF_CP + SZ_CP;                      // [16384]

// ---------------- P0: build padded bf16 image xpad[b][66][68][64] ----------------
__global__ __launch_bounds__(256) void k_xprep(const float* __restrict__ x,
                                               __hip_bfloat16* __restrict__ xp) {
  int t = threadIdx.x;
  int pos = blockIdx.x * 4 + (t >> 6);
  int c = t & 63;
  int b = pos / 4488;            // 66*68
  int rem = pos % 4488;
  int h = rem / 68, w = rem % 68;
  int y = h - 2;
  float v = 0.f;
  if (y >= 0 && y < 64 && w < 64 && c < NC)
    v = x[((size_t)b*NN + y*64 + w)*NC + c];
  xp[(size_t)pos*64 + c] = __float2bfloat16(v);
}

// ---------------- P1: weight prep into kstep-major layouts ----------------
// w1t2[((p*50 + ks)*64 + oc)*32 + ck], ks = dy*10 + k/32, k = dx*64+c (BN folded)
// w2t2[((p*8  + ks)*64 + oc)*32 + ck], ks = dy*4  + k/32
__global__ __launch_bounds__(256) void k_wprep(const float* __restrict__ w1,
                                               const float* __restrict__ w2,
                                               const float* __restrict__ g,
                                               const float* __restrict__ be,
                                               const float* __restrict__ mu,
                                               const float* __restrict__ va,
                                               __hip_bfloat16* __restrict__ w1t,
                                               float* __restrict__ bias,
                                               __hip_bfloat16* __restrict__ w2t) {
  int bx = blockIdx.x;
  if (bx < 75) {
    int p = bx / 25, tap = bx % 25, dy = tap / 5, dx = tap % 5;
    for (int i = threadIdx.x; i < 4096; i += 256) {
      int oc = i >> 6, c = i & 63;
      float v = 0.f;
      if (oc < NC && c < NC) {
        float sc = g[p*NC+oc] * rsqrtf(va[p*NC+oc] + 1e-5f);
        v = w1[(((size_t)p*NC + oc)*NC + c)*25 + tap] * sc;
      }
      int k = dx*64 + c;
      int ks = dy*10 + (k >> 5), ck = k & 31;
      w1t[(((size_t)p*50 + ks)*64 + oc)*32 + ck] = __float2bfloat16(v);
    }
    if (tap == 0 && threadIdx.x < 64) {
      int oc = threadIdx.x;
      float v = 0.f;
      if (oc < NC) {
        float sc = g[p*NC+oc] * rsqrtf(va[p*NC+oc] + 1e-5f);
        v = be[p*NC+oc] - mu[p*NC+oc]*sc;
      }
      bias[p*64 + oc] = v;
    }
  } else {
    int i2 = bx - 75;
    int p = i2 / 4, tap = i2 % 4, dy = tap >> 1, dx = tap & 1;
    for (int i = threadIdx.x; i < 4096; i += 256) {
      int oc = i >> 6, c = i & 63;
      float v = 0.f;
      if (oc < NC && c < NC)
        v = w2[(((size_t)p*NC + oc)*NC + c)*4 + tap];
      int k = dx*64 + c;
      int ks = dy*4 + (k >> 5), ck = k & 31;
      w2t[(((size_t)p*8 + ks)*64 + oc)*32 + ck] = __float2bfloat16(v);
    }
  }
}

// ---------------- P2: zero t1pad pad strips ----------------
__global__ __launch_bounds__(256) void k_zstrip(__hip_bfloat16* __restrict__ t1p) {
  int idx = blockIdx.x * 256 + threadIdx.x;
  int pb = idx >> 15, r = idx & 32767;
  int h2, w, c;
  if (r < 16896) {
    int hsel = r / 4224;
    h2 = hsel < 3 ? hsel : 65;
    int rem = r % 4224;
    w = rem >> 6; c = rem & 63;
  } else {
    int r2 = r - 16896;
    h2 = 3 + (r2 >> 8);
    int rem = r2 & 255;
    w = 62 + (rem >> 6); c = rem & 63;
  }
  t1p[(((size_t)pb*66 + h2)*66 + w)*64 + c] = __float2bfloat16(0.f);
}

__global__ __launch_bounds__(1024) void k_zero(float* __restrict__ out) {
  size_t i = (size_t)blockIdx.x * 1024 + threadIdx.x;
  if (i < (size_t)NB*NN*NC) out[i] = 0.f;
}

// ---------------- C1: conv1 as K=1600 GEMM, M_rep=2, full-unrolled ----------------
// grid (31, 12); block 4 waves: wave (w>>1) row-select, (w&1) 32-px half
__global__ __launch_bounds__(256, 2) void k_conv1m(const __hip_bfloat16* __restrict__ xp,
                                                   const __hip_bfloat16* __restrict__ w1t,
                                                   const float* __restrict__ bias,
                                                   __hip_bfloat16* __restrict__ t1p) {
  int w = threadIdx.x >> 6, lane = threadIdx.x & 63;
  int lr = lane & 15, lk = lane >> 4;
  int row = blockIdx.x * 2 + (w >> 1);          // output row 0..61
  int px0 = (w & 1) * 32;
  int pb = blockIdx.y; int p = pb / 4, b = pb % 4;

  // A[j][k] at xpad row (row+dy): j*64 + k, k = kk*32 + lk*8 (k = dx*64+c contiguity)
  const short* abase = (const short*)xp + (((size_t)b*66 + row)*68 + px0 + lr)*64 + lk*8;
  const short* wbase = (const short*)w1t + (size_t)p*50*2048 + lr*32 + lk*8;

  f32x4 acc[2][4];
#pragma unroll
  for (int m = 0; m < 2; ++m)
#pragma unroll
    for (int nt = 0; nt < 4; ++nt) acc[m][nt] = (f32x4){0.f,0.f,0.f,0.f};

#pragma unroll
  for (int dy = 0; dy < 5; ++dy) {
#pragma unroll
    for (int kk = 0; kk < 10; ++kk) {
      int ks = dy*10 + kk;
      const short* ar = abase + (size_t)dy*68*64 + kk*32;
      short8 a0 = *(const short8*)ar;
      short8 a1 = *(const short8*)(ar + 1024);            // +16 pixels
      const short* wr = wbase + (size_t)ks*2048;
#pragma unroll
      for (int nt = 0; nt < 4; ++nt) {
        short8 bf = *(const short8*)(wr + nt*512);
        acc[0][nt] = __builtin_amdgcn_mfma_f32_16x16x32_bf16(a0, bf, acc[0][nt], 0, 0, 0);
        acc[1][nt] = __builtin_amdgcn_mfma_f32_16x16x32_bf16(a1, bf, acc[1][nt], 0, 0, 0);
      }
    }
  }

  int h2 = row + 3;
  __hip_bfloat16* orow = t1p + (((size_t)(p*NB + b)*66 + h2)*66)*64;
#pragma unroll
  for (int nt = 0; nt < 4; ++nt) {
    float bv = bias[p*64 + nt*16 + lr];
#pragma unroll
    for (int m = 0; m < 2; ++m)
#pragma unroll
      for (int r = 0; r < 4; ++r) {
        int j1 = px0 + m*16 + lk*4 + r;
        float val = (j1 < 62) ? (acc[m][nt][r] + bv) : 0.f;
        orow[(size_t)j1*64 + nt*16 + lr] = __float2bfloat16(val);
      }
  }
}

// ---------------- C2: conv2 as K=256 GEMM, M_rep=2 -> qb/kb bf16, vv f32 ----------
// grid (32, 12); block 4 waves: 2 rows x 2 halves
__global__ __launch_bounds__(256, 2) void k_conv2m(const __hip_bfloat16* __restrict__ t1p,
                                                   const __hip_bfloat16* __restrict__ w2t,
                                                   __hip_bfloat16* __restrict__ qb,
                                                   __hip_bfloat16* __restrict__ kb,
                                                   float* __restrict__ vv) {
  int w = threadIdx.x >> 6, lane = threadIdx.x & 63;
  int lr = lane & 15, lk = lane >> 4;
  int row = blockIdx.x * 2 + (w >> 1);          // output row 0..63
  int px0 = (w & 1) * 32;
  int pb = blockIdx.y; int p = pb / 4, b = pb % 4;

  const short* abase = (const short*)t1p + (((size_t)(p*NB + b)*66 + row)*66 + px0 + lr)*64 + lk*8;
  const short* wbase = (const short*)w2t + (size_t)p*8*2048 + lr*32 + lk*8;

  f32x4 acc[2][4];
#pragma unroll
  for (int m = 0; m < 2; ++m)
#pragma unroll
    for (int nt = 0; nt < 4; ++nt) acc[m][nt] = (f32x4){0.f,0.f,0.f,0.f};

#pragma unroll
  for (int dy = 0; dy < 2; ++dy) {
#pragma unroll
    for (int kk = 0; kk < 4; ++kk) {
      int ks = dy*4 + kk;
      const short* ar = abase + (size_t)dy*66*64 + kk*32;
      short8 a0 = *(const short8*)ar;
      short8 a1 = *(const short8*)(ar + 1024);
      const short* wr = wbase + (size_t)ks*2048;
#pragma unroll
      for (int nt = 0; nt < 4; ++nt) {
        short8 bf = *(const short8*)(wr + nt*512);
        acc[0][nt] = __builtin_amdgcn_mfma_f32_16x16x32_bf16(a0, bf, acc[0][nt], 0, 0, 0);
        acc[1][nt] = __builtin_amdgcn_mfma_f32_16x16x32_bf16(a1, bf, acc[1][nt], 0, 0, 0);
      }
    }
  }

#pragma unroll
  for (int nt = 0; nt < 4; ++nt) {
#pragma unroll
    for (int m = 0; m < 2; ++m)
#pragma unroll
      for (int r = 0; r < 4; ++r) {
        int n = row*64 + px0 + m*16 + lk*4 + r;
        int oc = nt*16 + lr;
        float val = acc[m][nt][r];
        if (p == 0) {
          qb[((size_t)b*NN + n)*64 + oc] = __float2bfloat16(val * (F_SCALE * F_LOG2E));
        } else if (p == 1) {
          kb[((size_t)b*NN + n)*64 + oc] = __float2bfloat16(val);
        } else {
          vv[((size_t)b*NN + n)*64 + oc] = val;
        }
      }
  }
}

// ---------------- K3: MFMA row sums  L_t = sum_j exp2(q_t . k_j) ----------------
__global__ __launch_bounds__(256) void k_L(const __hip_bfloat16* __restrict__ qb,
                                           const __hip_bfloat16* __restrict__ kb,
                                           float* __restrict__ Lpart) {
  int w = threadIdx.x >> 6, lane = threadIdx.x & 63;
  int b = blockIdx.z, jc = blockIdx.y;
  int t0 = blockIdx.x * 64 + w * 16;
  int lr = lane & 15, lk = lane >> 4;

  const short* qrow = (const short*)qb + ((size_t)b*NN + t0 + lr)*64 + lk*8;
  short8 a0 = *(const short8*)qrow;
  short8 a1 = *(const short8*)(qrow + 32);
  const short* kptr = (const short*)kb + ((size_t)b*NN + jc*1024 + lr)*64 + lk*8;

  short8 nb0 = *(const short8*)kptr;
  short8 nb1 = *(const short8*)(kptr + 32);

  float rs[4] = {0.f, 0.f, 0.f, 0.f};
#pragma unroll 4
  for (int j = 0; j < 1024; j += 16) {
    short8 b0 = nb0, b1 = nb1;
    kptr += 16*64;
    if (j + 16 < 1024) { nb0 = *(const short8*)kptr; nb1 = *(const short8*)(kptr + 32); }
    f32x4 d = {0.f, 0.f, 0.f, 0.f};
    d = __builtin_amdgcn_mfma_f32_16x16x32_bf16(a0, b0, d, 0, 0, 0);
    d = __builtin_amdgcn_mfma_f32_16x16x32_bf16(a1, b1, d, 0, 0, 0);
#pragma unroll
    for (int r = 0; r < 4; ++r) rs[r] += exp2f(d[r]);
  }
#pragma unroll
  for (int r = 0; r < 4; ++r) {
#pragma unroll
    for (int m = 1; m < 16; m <<= 1) rs[r] += __shfl_xor(rs[r], m, 64);
  }
  if (lr == 0) {
    size_t base = (size_t)jc*(NB*NN) + (size_t)b*NN + t0 + lk*4;
#pragma unroll
    for (int r = 0; r < 4; ++r) Lpart[base + r] = rs[r];
  }
}

__global__ __launch_bounds__(256) void k_Lred(const float* __restrict__ Lpart,
                                              float* __restrict__ L,
                                              float* __restrict__ Linv) {
  int i = blockIdx.x * 256 + threadIdx.x;
  float sum = 0.f;
#pragma unroll
  for (int jc = 0; jc < 4; ++jc) sum += Lpart[(size_t)jc*(NB*NN) + i];
  L[i] = sum;
  Linv[i] = 1.f / sum;
}

// ---------------- K4: MFMA column totals  Ctot_j = sum_t exp2(.)/L_t ----------------
__global__ __launch_bounds__(256) void k_Ctot(const __hip_bfloat16* __restrict__ qb,
                                              const __hip_bfloat16* __restrict__ kb,
                                              const float* __restrict__ Linv,
                                              float* __restrict__ Cpart) {
  int w = threadIdx.x >> 6, lane = threadIdx.x & 63;
  int b = blockIdx.z, tc = blockIdx.y;
  int j0 = blockIdx.x * 64 + w * 16;
  int lr = lane & 15, lk = lane >> 4;

  const short* krow = (const short*)kb + ((size_t)b*NN + j0 + lr)*64 + lk*8;
  short8 b0 = *(const short8*)krow;
  short8 b1 = *(const short8*)(krow + 32);
  const short* qptr = (const short*)qb + ((size_t)b*NN + tc*1024 + lr)*64 + lk*8;
  const float* Li = Linv + (size_t)b*NN;

  short8 na0 = *(const short8*)qptr;
  short8 na1 = *(const short8*)(qptr + 32);

  float cacc = 0.f;
#pragma unroll 4
  for (int t = 0; t < 1024; t += 16) {
    short8 a0 = na0, a1 = na1;
    qptr += 16*64;
    if (t + 16 < 1024) { na0 = *(const short8*)qptr; na1 = *(const short8*)(qptr + 32); }
    f32x4 d = {0.f, 0.f, 0.f, 0.f};
    d = __builtin_amdgcn_mfma_f32_16x16x32_bf16(a0, b0, d, 0, 0, 0);
    d = __builtin_amdgcn_mfma_f32_16x16x32_bf16(a1, b1, d, 0, 0, 0);
    int r0 = tc*1024 + t + lk*4;
    cacc += exp2f(d[0])*Li[r0]   + exp2f(d[1])*Li[r0+1]
          + exp2f(d[2])*Li[r0+2] + exp2f(d[3])*Li[r0+3];
  }
  cacc += __shfl_xor(cacc, 16, 64);
  cacc += __shfl_xor(cacc, 32, 64);
  if (lane < 16) Cpart[(size_t)tc*(NB*NN) + (size_t)b*NN + j0 + lane] = cacc;
}

__global__ __launch_bounds__(256) void k_Cred(const float* __restrict__ Cpart,
                                              float* __restrict__ Ctot) {
  int i = blockIdx.x * 256 + threadIdx.x;
  float sum = 0.f;
#pragma unroll
  for (int tc = 0; tc < 4; ++tc) sum += Cpart[(size_t)tc*(NB*NN) + i];
  Ctot[i] = sum;
}

// ---------------- K5: spike fallback (exact serial walk, gated by column bound) ----
__global__ __launch_bounds__(256) void k_spike_fb(const __hip_bfloat16* __restrict__ qb,
                                                  const __hip_bfloat16* __restrict__ kb,
                                                  const float* __restrict__ L,
                                                  const float* __restrict__ Ctot,
                                                  const float* __restrict__ vv,
                                                  float* __restrict__ out) {
  int j = blockIdx.x * 256 + threadIdx.x;
  int b = blockIdx.y;
  if (F_DT * Ctot[(size_t)b*NN + j] < 0.5f) return;

  float kf[64];
  const __hip_bfloat16* kr = kb + ((size_t)b*NN + j)*64;
#pragma unroll
  for (int c = 0; c < 64; ++c) kf[c] = __bfloat162float(kr[c]);
  const __hip_bfloat16* Qb = qb + (size_t)b*NN*64;
  const float* Lb = L + (size_t)b*NN;
  const float* V  = vv + ((size_t)b*NN + j)*64;

  float cum = 0.f, Fprev = 0.f;
  for (int t = 0; t < NN; ++t) {
    const __hip_bfloat16* qr = Qb + (size_t)t*64;
    float dot = 0.f;
    for (int c = 0; c < 64; ++c) dot += __bfloat162float(qr[c]) * kf[c];
    float r = exp2f(dot) / Lb[t];
    cum += r * F_DT;
    float F = floorf(cum);
    if (F > Fprev) {
      float sv = (F - Fprev) / F_DT;
      float* orow = out + ((size_t)b*NN + t)*NC;
      for (int d = 0; d < NC; ++d) atomicAdd(orow + d, sv * V[d]);
      Fprev = F;
    }
  }
}

extern "C" void kernel_launch(void* const* d_in, const int* in_sizes, int n_in,
                              void* d_out, int out_size, void* d_ws, size_t ws_size,
                              hipStream_t stream) {
  const float* x  = (const float*)d_in[0];
  const float* w1 = (const float*)d_in[1];
  const float* w2 = (const float*)d_in[2];
  const float* g  = (const float*)d_in[3];
  const float* be = (const float*)d_in[4];
  const float* mu = (const float*)d_in[5];
  const float* va = (const float*)d_in[6];
  float* out = (float*)d_out;
  float* ws  = (float*)d_ws;

  __hip_bfloat16* xp  = (__hip_bfloat16*)(ws + OFF_XP);
  __hip_bfloat16* w1t = (__hip_bfloat16*)(ws + OFF_W1T);
  float*          bi  = ws + OFF_BI;
  __hip_bfloat16* w2t = (__hip_bfloat16*)(ws + OFF_W2T);
  __hip_bfloat16* t1p = (__hip_bfloat16*)(ws + OFF_T1P);
  __hip_bfloat16* qb  = (__hip_bfloat16*)(ws + OFF_QB);
  __hip_bfloat16* kb  = (__hip_bfloat16*)(ws + OFF_KB);
  float* vv = ws + OFF_VV;
  float* Lp = ws + OFF_LP;
  float* L  = ws + OFF_L;
  float* Li = ws + OFF_LI;
  float* Cp = ws + OFF_CP;
  float* Ct = ws + OFF_CT;

  k_xprep <<<dim3(4488), dim3(256), 0, stream>>>(x, xp);
  k_wprep <<<dim3(87),   dim3(256), 0, stream>>>(w1, w2, g, be, mu, va, w1t, bi, w2t);
  k_zstrip<<<dim3(1536), dim3(256), 0, stream>>>(t1p);
  k_zero  <<<dim3(800),  dim3(1024), 0, stream>>>(out);
  k_conv1m<<<dim3(31, 12), dim3(256), 0, stream>>>(xp, w1t, bi, t1p);
  k_conv2m<<<dim3(32, 12), dim3(256), 0, stream>>>(t1p, w2t, qb, kb, vv);
  k_L     <<<dim3(64, 4, NB), dim3(256), 0, stream>>>(qb, kb, Lp);
  k_Lred  <<<dim3(64), dim3(256), 0, stream>>>(Lp, L, Li);
  k_Ctot  <<<dim3(64, 4, NB), dim3(256), 0, stream>>>(qb, kb, Li, Cp);
  k_Cred  <<<dim3(64), dim3(256), 0, stream>>>(Cp, Ct);
  k_spike_fb<<<dim3(16, NB), dim3(256), 0, stream>>>(qb, kb, L, Ct, vv, out);
}

// Round 5
// 152.322 us; speedup vs baseline: 6.4816x; 1.3757x over previous
//
#include <hip/hip_runtime.h>
#include <hip/hip_bf16.h>
#include <math.h>

#define NB 4
#define NC 50
#define NN 4096

typedef __attribute__((ext_vector_type(8))) short short8;
typedef __attribute__((ext_vector_type(4))) float f32x4;

static constexpr float F_SCALE = 0.14142135623730951f;  // 50^-0.5
static constexpr float F_LOG2E = 1.44269504088896340f;  // exp(x)=exp2(x*log2e), folded into qb
static constexpr float F_DT = 0.001f;

// ---- workspace layout (f32 units) ----
static constexpr size_t OFF_XP  = 0;                                   // xpad [4][66][68][64] bf16
static constexpr size_t SZ_XP   = (size_t)4*66*68*64/2;
static constexpr size_t OFF_W1T = OFF_XP + SZ_XP;                      // w1t2 [3][50ks][64oc][32] bf16
static constexpr size_t SZ_W1T  = (size_t)3*25*64*64/2;
static constexpr size_t OFF_BI  = OFF_W1T + SZ_W1T;                    // bias [3][64] f32
static constexpr size_t SZ_BI   = 192;
static constexpr size_t OFF_W2T = OFF_BI + SZ_BI;                      // w2t2 [3][8ks][64oc][32] bf16
static constexpr size_t SZ_W2T  = (size_t)3*4*64*64/2;
static constexpr size_t OFF_T1P = OFF_W2T + SZ_W2T;                    // t1pad [12][66][66][64] bf16
static constexpr size_t SZ_T1P  = (size_t)12*66*66*64/2;
static constexpr size_t OFF_QB  = OFF_T1P + SZ_T1P;                    // qb [4][4096][64] bf16 (scaled*log2e)
static constexpr size_t SZ_QB   = (size_t)4*NN*64/2;
static constexpr size_t OFF_KB  = OFF_QB + SZ_QB;
static constexpr size_t SZ_KB   = SZ_QB;
static constexpr size_t OFF_VV  = OFF_KB + SZ_KB;                      // vv [4][4096][64] f32
static constexpr size_t SZ_VV   = (size_t)4*NN*64;
static constexpr size_t OFF_LP  = OFF_VV + SZ_VV;                      // Lpart [8][16384]
static constexpr size_t SZ_LP   = (size_t)8*NB*NN;
static constexpr size_t OFF_MP  = OFF_LP + SZ_LP;                      // Mpart [8][16384]
static constexpr size_t SZ_MP   = (size_t)8*NB*NN;
static constexpr size_t OFF_L   = OFF_MP + SZ_MP;                      // L [16384]
static constexpr size_t SZ_L    = (size_t)NB*NN;
static constexpr size_t OFF_GT  = OFF_L + SZ_L;                        // gate [1]

// ---------------- P0: build padded bf16 image xpad[b][66][68][64] ----------------
__global__ __launch_bounds__(256) void k_xprep(const float* __restrict__ x,
                                               __hip_bfloat16* __restrict__ xp) {
  int t = threadIdx.x;
  int pos = blockIdx.x * 4 + (t >> 6);
  int c = t & 63;
  int b = pos / 4488;            // 66*68
  int rem = pos % 4488;
  int h = rem / 68, w = rem % 68;
  int y = h - 2;
  float v = 0.f;
  if (y >= 0 && y < 64 && w < 64 && c < NC)
    v = x[((size_t)b*NN + y*64 + w)*NC + c];
  xp[(size_t)pos*64 + c] = __float2bfloat16(v);
}

// ---------------- P1: weight prep into kstep-major layouts ----------------
__global__ __launch_bounds__(256) void k_wprep(const float* __restrict__ w1,
                                               const float* __restrict__ w2,
                                               const float* __restrict__ g,
                                               const float* __restrict__ be,
                                               const float* __restrict__ mu,
                                               const float* __restrict__ va,
                                               __hip_bfloat16* __restrict__ w1t,
                                               float* __restrict__ bias,
                                               __hip_bfloat16* __restrict__ w2t) {
  int bx = blockIdx.x;
  if (bx < 75) {
    int p = bx / 25, tap = bx % 25, dy = tap / 5, dx = tap % 5;
    for (int i = threadIdx.x; i < 4096; i += 256) {
      int oc = i >> 6, c = i & 63;
      float v = 0.f;
      if (oc < NC && c < NC) {
        float sc = g[p*NC+oc] * rsqrtf(va[p*NC+oc] + 1e-5f);
        v = w1[(((size_t)p*NC + oc)*NC + c)*25 + tap] * sc;
      }
      int k = dx*64 + c;
      int ks = dy*10 + (k >> 5), ck = k & 31;
      w1t[(((size_t)p*50 + ks)*64 + oc)*32 + ck] = __float2bfloat16(v);
    }
    if (tap == 0 && threadIdx.x < 64) {
      int oc = threadIdx.x;
      float v = 0.f;
      if (oc < NC) {
        float sc = g[p*NC+oc] * rsqrtf(va[p*NC+oc] + 1e-5f);
        v = be[p*NC+oc] - mu[p*NC+oc]*sc;
      }
      bias[p*64 + oc] = v;
    }
  } else {
    int i2 = bx - 75;
    int p = i2 / 4, tap = i2 % 4, dy = tap >> 1, dx = tap & 1;
    for (int i = threadIdx.x; i < 4096; i += 256) {
      int oc = i >> 6, c = i & 63;
      float v = 0.f;
      if (oc < NC && c < NC)
        v = w2[(((size_t)p*NC + oc)*NC + c)*4 + tap];
      int k = dx*64 + c;
      int ks = dy*4 + (k >> 5), ck = k & 31;
      w2t[(((size_t)p*8 + ks)*64 + oc)*32 + ck] = __float2bfloat16(v);
    }
  }
}

// ---------------- P2: zero t1pad pad strips ----------------
__global__ __launch_bounds__(256) void k_zstrip(__hip_bfloat16* __restrict__ t1p) {
  int idx = blockIdx.x * 256 + threadIdx.x;
  int pb = idx >> 15, r = idx & 32767;
  int h2, w, c;
  if (r < 16896) {
    int hsel = r / 4224;
    h2 = hsel < 3 ? hsel : 65;
    int rem = r % 4224;
    w = rem >> 6; c = rem & 63;
  } else {
    int r2 = r - 16896;
    h2 = 3 + (r2 >> 8);
    int rem = r2 & 255;
    w = 62 + (rem >> 6); c = rem & 63;
  }
  t1p[(((size_t)pb*66 + h2)*66 + w)*64 + c] = __float2bfloat16(0.f);
}

// zero out + gate
__global__ __launch_bounds__(1024) void k_zero(float* __restrict__ out,
                                               float* __restrict__ gate) {
  size_t i = (size_t)blockIdx.x * 1024 + threadIdx.x;
  if (i < (size_t)NB*NN*NC) out[i] = 0.f;
  if (i == 0) gate[0] = 0.f;
}

// ---------------- C1: conv1 as K=1600 GEMM, M_rep=2, full-unrolled ----------------
__global__ __launch_bounds__(256, 2) void k_conv1m(const __hip_bfloat16* __restrict__ xp,
                                                   const __hip_bfloat16* __restrict__ w1t,
                                                   const float* __restrict__ bias,
                                                   __hip_bfloat16* __restrict__ t1p) {
  int w = threadIdx.x >> 6, lane = threadIdx.x & 63;
  int lr = lane & 15, lk = lane >> 4;
  int row = blockIdx.x * 2 + (w >> 1);          // output row 0..61
  int px0 = (w & 1) * 32;
  int pb = blockIdx.y; int p = pb / 4, b = pb % 4;

  const short* abase = (const short*)xp + (((size_t)b*66 + row)*68 + px0 + lr)*64 + lk*8;
  const short* wbase = (const short*)w1t + (size_t)p*50*2048 + lr*32 + lk*8;

  f32x4 acc[2][4];
#pragma unroll
  for (int m = 0; m < 2; ++m)
#pragma unroll
    for (int nt = 0; nt < 4; ++nt) acc[m][nt] = (f32x4){0.f,0.f,0.f,0.f};

#pragma unroll
  for (int dy = 0; dy < 5; ++dy) {
#pragma unroll
    for (int kk = 0; kk < 10; ++kk) {
      int ks = dy*10 + kk;
      const short* ar = abase + (size_t)dy*68*64 + kk*32;
      short8 a0 = *(const short8*)ar;
      short8 a1 = *(const short8*)(ar + 1024);            // +16 pixels
      const short* wr = wbase + (size_t)ks*2048;
#pragma unroll
      for (int nt = 0; nt < 4; ++nt) {
        short8 bf = *(const short8*)(wr + nt*512);
        acc[0][nt] = __builtin_amdgcn_mfma_f32_16x16x32_bf16(a0, bf, acc[0][nt], 0, 0, 0);
        acc[1][nt] = __builtin_amdgcn_mfma_f32_16x16x32_bf16(a1, bf, acc[1][nt], 0, 0, 0);
      }
    }
  }

  int h2 = row + 3;
  __hip_bfloat16* orow = t1p + (((size_t)(p*NB + b)*66 + h2)*66)*64;
#pragma unroll
  for (int nt = 0; nt < 4; ++nt) {
    float bv = bias[p*64 + nt*16 + lr];
#pragma unroll
    for (int m = 0; m < 2; ++m)
#pragma unroll
      for (int r = 0; r < 4; ++r) {
        int j1 = px0 + m*16 + lk*4 + r;
        float val = (j1 < 62) ? (acc[m][nt][r] + bv) : 0.f;
        orow[(size_t)j1*64 + nt*16 + lr] = __float2bfloat16(val);
      }
  }
}

// ---------------- C2: conv2 as K=256 GEMM, M_rep=2 -> qb/kb bf16, vv f32 ----------
__global__ __launch_bounds__(256, 2) void k_conv2m(const __hip_bfloat16* __restrict__ t1p,
                                                   const __hip_bfloat16* __restrict__ w2t,
                                                   __hip_bfloat16* __restrict__ qb,
                                                   __hip_bfloat16* __restrict__ kb,
                                                   float* __restrict__ vv) {
  int w = threadIdx.x >> 6, lane = threadIdx.x & 63;
  int lr = lane & 15, lk = lane >> 4;
  int row = blockIdx.x * 2 + (w >> 1);          // output row 0..63
  int px0 = (w & 1) * 32;
  int pb = blockIdx.y; int p = pb / 4, b = pb % 4;

  const short* abase = (const short*)t1p + (((size_t)(p*NB + b)*66 + row)*66 + px0 + lr)*64 + lk*8;
  const short* wbase = (const short*)w2t + (size_t)p*8*2048 + lr*32 + lk*8;

  f32x4 acc[2][4];
#pragma unroll
  for (int m = 0; m < 2; ++m)
#pragma unroll
    for (int nt = 0; nt < 4; ++nt) acc[m][nt] = (f32x4){0.f,0.f,0.f,0.f};

#pragma unroll
  for (int dy = 0; dy < 2; ++dy) {
#pragma unroll
    for (int kk = 0; kk < 4; ++kk) {
      int ks = dy*4 + kk;
      const short* ar = abase + (size_t)dy*66*64 + kk*32;
      short8 a0 = *(const short8*)ar;
      short8 a1 = *(const short8*)(ar + 1024);
      const short* wr = wbase + (size_t)ks*2048;
#pragma unroll
      for (int nt = 0; nt < 4; ++nt) {
        short8 bf = *(const short8*)(wr + nt*512);
        acc[0][nt] = __builtin_amdgcn_mfma_f32_16x16x32_bf16(a0, bf, acc[0][nt], 0, 0, 0);
        acc[1][nt] = __builtin_amdgcn_mfma_f32_16x16x32_bf16(a1, bf, acc[1][nt], 0, 0, 0);
      }
    }
  }

#pragma unroll
  for (int nt = 0; nt < 4; ++nt) {
#pragma unroll
    for (int m = 0; m < 2; ++m)
#pragma unroll
      for (int r = 0; r < 4; ++r) {
        int n = row*64 + px0 + m*16 + lk*4 + r;
        int oc = nt*16 + lr;
        float val = acc[m][nt][r];
        if (p == 0) {
          qb[((size_t)b*NN + n)*64 + oc] = __float2bfloat16(val * (F_SCALE * F_LOG2E));
        } else if (p == 1) {
          kb[((size_t)b*NN + n)*64 + oc] = __float2bfloat16(val);
        } else {
          vv[((size_t)b*NN + n)*64 + oc] = val;
        }
      }
  }
}

// ---------------- K3: MFMA row sums + row max over j-chunk ----------------
// grid (64 t-tiles, 8 jc, NB), block 256 = 4 waves (same jc -> shared k-stream via L1)
// per iter: 2 independent j-tiles (4 MFMAs in 2 chains, 8 exps), 2-tile prefetch
__global__ __launch_bounds__(256) void k_L(const __hip_bfloat16* __restrict__ qb,
                                           const __hip_bfloat16* __restrict__ kb,
                                           float* __restrict__ Lpart,
                                           float* __restrict__ Mpart) {
  int w = threadIdx.x >> 6, lane = threadIdx.x & 63;
  int b = blockIdx.z, jc = blockIdx.y;
  int t0 = blockIdx.x * 64 + w * 16;
  int lr = lane & 15, lk = lane >> 4;

  const short* qrow = (const short*)qb + ((size_t)b*NN + t0 + lr)*64 + lk*8;
  short8 a0 = *(const short8*)qrow;
  short8 a1 = *(const short8*)(qrow + 32);
  const short* kp = (const short*)kb + ((size_t)b*NN + jc*512 + lr)*64 + lk*8;

  short8 n00 = *(const short8*)kp;
  short8 n01 = *(const short8*)(kp + 32);
  short8 n10 = *(const short8*)(kp + 1024);        // +16 rows
  short8 n11 = *(const short8*)(kp + 1024 + 32);

  float rs[4] = {0.f, 0.f, 0.f, 0.f};
  float mx[4] = {-3e38f, -3e38f, -3e38f, -3e38f};
#pragma unroll 2
  for (int j = 0; j < 512; j += 32) {
    short8 b00 = n00, b01 = n01, b10 = n10, b11 = n11;
    kp += 32*64;
    if (j + 32 < 512) {
      n00 = *(const short8*)kp;
      n01 = *(const short8*)(kp + 32);
      n10 = *(const short8*)(kp + 1024);
      n11 = *(const short8*)(kp + 1024 + 32);
    }
    f32x4 d0 = {0.f,0.f,0.f,0.f}, d1 = {0.f,0.f,0.f,0.f};
    d0 = __builtin_amdgcn_mfma_f32_16x16x32_bf16(a0, b00, d0, 0, 0, 0);
    d0 = __builtin_amdgcn_mfma_f32_16x16x32_bf16(a1, b01, d0, 0, 0, 0);
    d1 = __builtin_amdgcn_mfma_f32_16x16x32_bf16(a0, b10, d1, 0, 0, 0);
    d1 = __builtin_amdgcn_mfma_f32_16x16x32_bf16(a1, b11, d1, 0, 0, 0);
#pragma unroll
    for (int r = 0; r < 4; ++r) {
      rs[r] += exp2f(d0[r]) + exp2f(d1[r]);
      mx[r] = fmaxf(mx[r], fmaxf(d0[r], d1[r]));
    }
  }
#pragma unroll
  for (int r = 0; r < 4; ++r) {
#pragma unroll
    for (int m = 1; m < 16; m <<= 1) {
      rs[r] += __shfl_xor(rs[r], m, 64);
      mx[r] = fmaxf(mx[r], __shfl_xor(mx[r], m, 64));
    }
  }
  if (lr == 0) {
    size_t base = (size_t)jc*(NB*NN) + (size_t)b*NN + t0 + lk*4;
#pragma unroll
    for (int r = 0; r < 4; ++r) {
      Lpart[base + r] = rs[r];
      Mpart[base + r] = mx[r];
    }
  }
}

// ---------------- K3b: reduce L, M; accumulate gate G = sum_t exp2(M_t)/L_t -------
__global__ __launch_bounds__(256) void k_Lred(const float* __restrict__ Lpart,
                                              const float* __restrict__ Mpart,
                                              float* __restrict__ L,
                                              float* __restrict__ gate) {
  int i = blockIdx.x * 256 + threadIdx.x;   // 16384
  float sum = 0.f, mx = -3e38f;
#pragma unroll
  for (int jc = 0; jc < 8; ++jc) {
    sum += Lpart[(size_t)jc*(NB*NN) + i];
    mx = fmaxf(mx, Mpart[(size_t)jc*(NB*NN) + i]);
  }
  L[i] = sum;
  float m = exp2f(mx) / sum;   // upper bound on any column's r at row i
  __shared__ float red[256];
  red[threadIdx.x] = m;
  __syncthreads();
  for (int s = 128; s > 0; s >>= 1) {
    if (threadIdx.x < s) red[threadIdx.x] += red[threadIdx.x + s];
    __syncthreads();
  }
  if (threadIdx.x == 0) atomicAdd(gate, red[0]);
}

// ---------------- K5: spike fallback (exact serial walk; gate = sum_t max_j r) ----
// Sound: r_tj <= exp2(M_t)/L_t, so every column mass <= gate. If dt*gate < 0.99,
// v_j stays < 1 forever -> floor never increments -> out stays 0.
__global__ __launch_bounds__(256) void k_spike_fb(const __hip_bfloat16* __restrict__ qb,
                                                  const __hip_bfloat16* __restrict__ kb,
                                                  const float* __restrict__ L,
                                                  const float* __restrict__ gate,
                                                  const float* __restrict__ vv,
                                                  float* __restrict__ out) {
  if (F_DT * gate[0] < 0.99f) return;
  int j = blockIdx.x * 256 + threadIdx.x;
  int b = blockIdx.y;

  float kf[64];
  const __hip_bfloat16* kr = kb + ((size_t)b*NN + j)*64;
#pragma unroll
  for (int c = 0; c < 64; ++c) kf[c] = __bfloat162float(kr[c]);
  const __hip_bfloat16* Qb = qb + (size_t)b*NN*64;
  const float* Lb = L + (size_t)b*NN;
  const float* V  = vv + ((size_t)b*NN + j)*64;

  float cum = 0.f, Fprev = 0.f;
  for (int t = 0; t < NN; ++t) {
    const __hip_bfloat16* qr = Qb + (size_t)t*64;
    float dot = 0.f;
    for (int c = 0; c < 64; ++c) dot += __bfloat162float(qr[c]) * kf[c];
    float r = exp2f(dot) / Lb[t];
    cum += r * F_DT;
    float F = floorf(cum);
    if (F > Fprev) {
      float sv = (F - Fprev) / F_DT;
      float* orow = out + ((size_t)b*NN + t)*NC;
      for (int d = 0; d < NC; ++d) atomicAdd(orow + d, sv * V[d]);
      Fprev = F;
    }
  }
}

extern "C" void kernel_launch(void* const* d_in, const int* in_sizes, int n_in,
                              void* d_out, int out_size, void* d_ws, size_t ws_size,
                              hipStream_t stream) {
  const float* x  = (const float*)d_in[0];
  const float* w1 = (const float*)d_in[1];
  const float* w2 = (const float*)d_in[2];
  const float* g  = (const float*)d_in[3];
  const float* be = (const float*)d_in[4];
  const float* mu = (const float*)d_in[5];
  const float* va = (const float*)d_in[6];
  float* out = (float*)d_out;
  float* ws  = (float*)d_ws;

  __hip_bfloat16* xp  = (__hip_bfloat16*)(ws + OFF_XP);
  __hip_bfloat16* w1t = (__hip_bfloat16*)(ws + OFF_W1T);
  float*          bi  = ws + OFF_BI;
  __hip_bfloat16* w2t = (__hip_bfloat16*)(ws + OFF_W2T);
  __hip_bfloat16* t1p = (__hip_bfloat16*)(ws + OFF_T1P);
  __hip_bfloat16* qb  = (__hip_bfloat16*)(ws + OFF_QB);
  __hip_bfloat16* kb  = (__hip_bfloat16*)(ws + OFF_KB);
  float* vv = ws + OFF_VV;
  float* Lp = ws + OFF_LP;
  float* Mp = ws + OFF_MP;
  float* L  = ws + OFF_L;
  float* gt = ws + OFF_GT;

  k_xprep <<<dim3(4488), dim3(256), 0, stream>>>(x, xp);
  k_wprep <<<dim3(87),   dim3(256), 0, stream>>>(w1, w2, g, be, mu, va, w1t, bi, w2t);
  k_zstrip<<<dim3(1536), dim3(256), 0, stream>>>(t1p);
  k_zero  <<<dim3(800),  dim3(1024), 0, stream>>>(out, gt);
  k_conv1m<<<dim3(31, 12), dim3(256), 0, stream>>>(xp, w1t, bi, t1p);
  k_conv2m<<<dim3(32, 12), dim3(256), 0, stream>>>(t1p, w2t, qb, kb, vv);
  k_L     <<<dim3(64, 8, NB), dim3(256), 0, stream>>>(qb, kb, Lp, Mp);
  k_Lred  <<<dim3(64), dim3(256), 0, stream>>>(Lp, Mp, L, gt);
  k_spike_fb<<<dim3(16, NB), dim3(256), 0, stream>>>(qb, kb, L, gt, vv, out);
}

// Round 6
// 93.800 us; speedup vs baseline: 10.5256x; 1.6239x over previous
//
#include <hip/hip_runtime.h>
#include <hip/hip_bf16.h>
#include <math.h>

#define NB 4
#define NC 50
#define NN 4096

typedef __attribute__((ext_vector_type(8))) short short8;
typedef __attribute__((ext_vector_type(4))) float f32x4;

static constexpr float F_SCALE = 0.14142135623730951f;  // 50^-0.5
static constexpr float F_LOG2E = 1.44269504088896340f;  // exp(x)=exp2(x*log2e), folded into qb
static constexpr float F_DT = 0.001f;

// ---- workspace layout (f32 units) ----
static constexpr size_t OFF_XP  = 0;                                   // xpad [4][66][68][64] bf16
static constexpr size_t SZ_XP   = (size_t)4*66*68*64/2;
static constexpr size_t OFF_W1T = OFF_XP + SZ_XP;                      // w1t2 [3][50ks][64oc][32] bf16
static constexpr size_t SZ_W1T  = (size_t)3*25*64*64/2;
static constexpr size_t OFF_BI  = OFF_W1T + SZ_W1T;                    // bias [3][64] f32
static constexpr size_t SZ_BI   = 192;
static constexpr size_t OFF_W2T = OFF_BI + SZ_BI;                      // w2t2 [3][8ks][64oc][32] bf16
static constexpr size_t SZ_W2T  = (size_t)3*4*64*64/2;
static constexpr size_t OFF_T1P = OFF_W2T + SZ_W2T;                    // t1pad [12][66][66][64] bf16
static constexpr size_t SZ_T1P  = (size_t)12*66*66*64/2;
static constexpr size_t OFF_QB  = OFF_T1P + SZ_T1P;                    // qb [4][4096][64] bf16 (scaled*log2e)
static constexpr size_t SZ_QB   = (size_t)4*NN*64/2;
static constexpr size_t OFF_KB  = OFF_QB + SZ_QB;
static constexpr size_t SZ_KB   = SZ_QB;
static constexpr size_t OFF_VV  = OFF_KB + SZ_KB;                      // vv [4][4096][64] f32
static constexpr size_t SZ_VV   = (size_t)4*NN*64;
static constexpr size_t OFF_LP  = OFF_VV + SZ_VV;                      // Lpart [8][16384]
static constexpr size_t SZ_LP   = (size_t)8*NB*NN;
static constexpr size_t OFF_MP  = OFF_LP + SZ_LP;                      // Mpart [8][16384]
static constexpr size_t SZ_MP   = (size_t)8*NB*NN;
static constexpr size_t OFF_L   = OFF_MP + SZ_MP;                      // L [16384]
static constexpr size_t SZ_L    = (size_t)NB*NN;
static constexpr size_t OFF_GT  = OFF_L + SZ_L;                        // gateL [1]
static constexpr size_t OFF_QN2 = OFF_GT + 1;                          // qnorm2 [16384]
static constexpr size_t SZ_QN2  = (size_t)NB*NN;
static constexpr size_t OFF_KMX = OFF_QN2 + SZ_QN2;                    // kmax2 bits [1]
static constexpr size_t OFF_GN  = OFF_KMX + 1;                         // gateN [1]

__device__ __forceinline__ float bf2f(short s) {
  return __uint_as_float(((unsigned)(unsigned short)s) << 16);
}

// ---------------- P0: build padded bf16 image xpad[b][66][68][64] ----------------
__global__ __launch_bounds__(256) void k_xprep(const float* __restrict__ x,
                                               __hip_bfloat16* __restrict__ xp) {
  int t = threadIdx.x;
  int pos = blockIdx.x * 4 + (t >> 6);
  int c = t & 63;
  int b = pos / 4488;            // 66*68
  int rem = pos % 4488;
  int h = rem / 68, w = rem % 68;
  int y = h - 2;
  float v = 0.f;
  if (y >= 0 && y < 64 && w < 64 && c < NC)
    v = x[((size_t)b*NN + y*64 + w)*NC + c];
  xp[(size_t)pos*64 + c] = __float2bfloat16(v);
}

// ---------------- P1: weight prep into kstep-major layouts ----------------
__global__ __launch_bounds__(256) void k_wprep(const float* __restrict__ w1,
                                               const float* __restrict__ w2,
                                               const float* __restrict__ g,
                                               const float* __restrict__ be,
                                               const float* __restrict__ mu,
                                               const float* __restrict__ va,
                                               __hip_bfloat16* __restrict__ w1t,
                                               float* __restrict__ bias,
                                               __hip_bfloat16* __restrict__ w2t) {
  int bx = blockIdx.x;
  if (bx < 75) {
    int p = bx / 25, tap = bx % 25, dy = tap / 5, dx = tap % 5;
    for (int i = threadIdx.x; i < 4096; i += 256) {
      int oc = i >> 6, c = i & 63;
      float v = 0.f;
      if (oc < NC && c < NC) {
        float sc = g[p*NC+oc] * rsqrtf(va[p*NC+oc] + 1e-5f);
        v = w1[(((size_t)p*NC + oc)*NC + c)*25 + tap] * sc;
      }
      int k = dx*64 + c;
      int ks = dy*10 + (k >> 5), ck = k & 31;
      w1t[(((size_t)p*50 + ks)*64 + oc)*32 + ck] = __float2bfloat16(v);
    }
    if (tap == 0 && threadIdx.x < 64) {
      int oc = threadIdx.x;
      float v = 0.f;
      if (oc < NC) {
        float sc = g[p*NC+oc] * rsqrtf(va[p*NC+oc] + 1e-5f);
        v = be[p*NC+oc] - mu[p*NC+oc]*sc;
      }
      bias[p*64 + oc] = v;
    }
  } else {
    int i2 = bx - 75;
    int p = i2 / 4, tap = i2 % 4, dy = tap >> 1, dx = tap & 1;
    for (int i = threadIdx.x; i < 4096; i += 256) {
      int oc = i >> 6, c = i & 63;
      float v = 0.f;
      if (oc < NC && c < NC)
        v = w2[(((size_t)p*NC + oc)*NC + c)*4 + tap];
      int k = dx*64 + c;
      int ks = dy*4 + (k >> 5), ck = k & 31;
      w2t[(((size_t)p*8 + ks)*64 + oc)*32 + ck] = __float2bfloat16(v);
    }
  }
}

// ---------------- P2: zero t1pad pad strips ----------------
__global__ __launch_bounds__(256) void k_zstrip(__hip_bfloat16* __restrict__ t1p) {
  int idx = blockIdx.x * 256 + threadIdx.x;
  int pb = idx >> 15, r = idx & 32767;
  int h2, w, c;
  if (r < 16896) {
    int hsel = r / 4224;
    h2 = hsel < 3 ? hsel : 65;
    int rem = r % 4224;
    w = rem >> 6; c = rem & 63;
  } else {
    int r2 = r - 16896;
    h2 = 3 + (r2 >> 8);
    int rem = r2 & 255;
    w = 62 + (rem >> 6); c = rem & 63;
  }
  t1p[(((size_t)pb*66 + h2)*66 + w)*64 + c] = __float2bfloat16(0.f);
}

// zero out + scalars
__global__ __launch_bounds__(1024) void k_zero(float* __restrict__ out,
                                               float* __restrict__ gateL,
                                               float* __restrict__ gateN,
                                               int* __restrict__ kmx) {
  size_t i = (size_t)blockIdx.x * 1024 + threadIdx.x;
  if (i < (size_t)NB*NN*NC) out[i] = 0.f;
  if (i == 0) { gateL[0] = 0.f; gateN[0] = 0.f; kmx[0] = 0; }
}

// ---------------- C1: conv1 as K=1600 GEMM, M_rep=2, full-unrolled ----------------
__global__ __launch_bounds__(256, 2) void k_conv1m(const __hip_bfloat16* __restrict__ xp,
                                                   const __hip_bfloat16* __restrict__ w1t,
                                                   const float* __restrict__ bias,
                                                   __hip_bfloat16* __restrict__ t1p) {
  int w = threadIdx.x >> 6, lane = threadIdx.x & 63;
  int lr = lane & 15, lk = lane >> 4;
  int row = blockIdx.x * 2 + (w >> 1);          // output row 0..61
  int px0 = (w & 1) * 32;
  int pb = blockIdx.y; int p = pb / 4, b = pb % 4;

  const short* abase = (const short*)xp + (((size_t)b*66 + row)*68 + px0 + lr)*64 + lk*8;
  const short* wbase = (const short*)w1t + (size_t)p*50*2048 + lr*32 + lk*8;

  f32x4 acc[2][4];
#pragma unroll
  for (int m = 0; m < 2; ++m)
#pragma unroll
    for (int nt = 0; nt < 4; ++nt) acc[m][nt] = (f32x4){0.f,0.f,0.f,0.f};

#pragma unroll
  for (int dy = 0; dy < 5; ++dy) {
#pragma unroll
    for (int kk = 0; kk < 10; ++kk) {
      int ks = dy*10 + kk;
      const short* ar = abase + (size_t)dy*68*64 + kk*32;
      short8 a0 = *(const short8*)ar;
      short8 a1 = *(const short8*)(ar + 1024);            // +16 pixels
      const short* wr = wbase + (size_t)ks*2048;
#pragma unroll
      for (int nt = 0; nt < 4; ++nt) {
        short8 bf = *(const short8*)(wr + nt*512);
        acc[0][nt] = __builtin_amdgcn_mfma_f32_16x16x32_bf16(a0, bf, acc[0][nt], 0, 0, 0);
        acc[1][nt] = __builtin_amdgcn_mfma_f32_16x16x32_bf16(a1, bf, acc[1][nt], 0, 0, 0);
      }
    }
  }

  int h2 = row + 3;
  __hip_bfloat16* orow = t1p + (((size_t)(p*NB + b)*66 + h2)*66)*64;
#pragma unroll
  for (int nt = 0; nt < 4; ++nt) {
    float bv = bias[p*64 + nt*16 + lr];
#pragma unroll
    for (int m = 0; m < 2; ++m)
#pragma unroll
      for (int r = 0; r < 4; ++r) {
        int j1 = px0 + m*16 + lk*4 + r;
        float val = (j1 < 62) ? (acc[m][nt][r] + bv) : 0.f;
        orow[(size_t)j1*64 + nt*16 + lr] = __float2bfloat16(val);
      }
  }
}

// ---------------- C2: conv2 as K=256 GEMM, M_rep=2 -> qb/kb bf16, vv f32 ----------
__global__ __launch_bounds__(256, 2) void k_conv2m(const __hip_bfloat16* __restrict__ t1p,
                                                   const __hip_bfloat16* __restrict__ w2t,
                                                   __hip_bfloat16* __restrict__ qb,
                                                   __hip_bfloat16* __restrict__ kb,
                                                   float* __restrict__ vv) {
  int w = threadIdx.x >> 6, lane = threadIdx.x & 63;
  int lr = lane & 15, lk = lane >> 4;
  int row = blockIdx.x * 2 + (w >> 1);          // output row 0..63
  int px0 = (w & 1) * 32;
  int pb = blockIdx.y; int p = pb / 4, b = pb % 4;

  const short* abase = (const short*)t1p + (((size_t)(p*NB + b)*66 + row)*66 + px0 + lr)*64 + lk*8;
  const short* wbase = (const short*)w2t + (size_t)p*8*2048 + lr*32 + lk*8;

  f32x4 acc[2][4];
#pragma unroll
  for (int m = 0; m < 2; ++m)
#pragma unroll
    for (int nt = 0; nt < 4; ++nt) acc[m][nt] = (f32x4){0.f,0.f,0.f,0.f};

#pragma unroll
  for (int dy = 0; dy < 2; ++dy) {
#pragma unroll
    for (int kk = 0; kk < 4; ++kk) {
      int ks = dy*4 + kk;
      const short* ar = abase + (size_t)dy*66*64 + kk*32;
      short8 a0 = *(const short8*)ar;
      short8 a1 = *(const short8*)(ar + 1024);
      const short* wr = wbase + (size_t)ks*2048;
#pragma unroll
      for (int nt = 0; nt < 4; ++nt) {
        short8 bf = *(const short8*)(wr + nt*512);
        acc[0][nt] = __builtin_amdgcn_mfma_f32_16x16x32_bf16(a0, bf, acc[0][nt], 0, 0, 0);
        acc[1][nt] = __builtin_amdgcn_mfma_f32_16x16x32_bf16(a1, bf, acc[1][nt], 0, 0, 0);
      }
    }
  }

#pragma unroll
  for (int nt = 0; nt < 4; ++nt) {
#pragma unroll
    for (int m = 0; m < 2; ++m)
#pragma unroll
      for (int r = 0; r < 4; ++r) {
        int n = row*64 + px0 + m*16 + lk*4 + r;
        int oc = nt*16 + lr;
        float val = acc[m][nt][r];
        if (p == 0) {
          qb[((size_t)b*NN + n)*64 + oc] = __float2bfloat16(val * (F_SCALE * F_LOG2E));
        } else if (p == 1) {
          kb[((size_t)b*NN + n)*64 + oc] = __float2bfloat16(val);
        } else {
          vv[((size_t)b*NN + n)*64 + oc] = val;
        }
      }
  }
}

// ---------------- G1: row norms of qb, kb; Kmax2 via atomicMax on bits ------------
__global__ __launch_bounds__(256) void k_gateA(const __hip_bfloat16* __restrict__ qb,
                                               const __hip_bfloat16* __restrict__ kb,
                                               float* __restrict__ qn2,
                                               int* __restrict__ kmx) {
  int i = blockIdx.x * 256 + threadIdx.x;   // row over all batches: 16384
  const short8* qr = (const short8*)((const short*)qb + (size_t)i*64);
  const short8* kr = (const short8*)((const short*)kb + (size_t)i*64);
  float sq = 0.f, sk = 0.f;
#pragma unroll
  for (int u = 0; u < 8; ++u) {
    short8 v = qr[u], w = kr[u];
#pragma unroll
    for (int e = 0; e < 8; ++e) {
      float a = bf2f(v[e]); sq += a*a;
      float c = bf2f(w[e]); sk += c*c;
    }
  }
  qn2[i] = sq;
#pragma unroll
  for (int m = 1; m < 64; m <<= 1) sk = fmaxf(sk, __shfl_xor(sk, m, 64));
  __shared__ float smax[4];
  if ((threadIdx.x & 63) == 0) smax[threadIdx.x >> 6] = sk;
  __syncthreads();
  if (threadIdx.x == 0) {
    float mm = fmaxf(fmaxf(smax[0], smax[1]), fmaxf(smax[2], smax[3]));
    atomicMax(kmx, __float_as_int(mm));   // norms >= 0: bit order == float order
  }
}

// ---------------- G2: gateN = sum_t exp2(2*|q~_t|*Kmax)/N  (>= any column mass) ---
__global__ __launch_bounds__(256) void k_gateB(const float* __restrict__ qn2,
                                               const int* __restrict__ kmx,
                                               float* __restrict__ gateN) {
  int i = blockIdx.x * 256 + threadIdx.x;
  float km = sqrtf(__int_as_float(kmx[0]));
  float term = exp2f(2.f * sqrtf(qn2[i]) * km) * (1.f / (float)NN);
  __shared__ float red[256];
  red[threadIdx.x] = term;
  __syncthreads();
  for (int s = 128; s > 0; s >>= 1) {
    if (threadIdx.x < s) red[threadIdx.x] += red[threadIdx.x + s];
    __syncthreads();
  }
  if (threadIdx.x == 0) atomicAdd(gateN, red[0]);
}

// ---------------- K3: MFMA row sums + row max (only if norm gate fails) -----------
__global__ __launch_bounds__(256) void k_L(const __hip_bfloat16* __restrict__ qb,
                                           const __hip_bfloat16* __restrict__ kb,
                                           const float* __restrict__ gateN,
                                           float* __restrict__ Lpart,
                                           float* __restrict__ Mpart) {
  if (F_DT * gateN[0] < 0.99f) return;    // provably no spikes -> L never consumed
  int w = threadIdx.x >> 6, lane = threadIdx.x & 63;
  int b = blockIdx.z, jc = blockIdx.y;
  int t0 = blockIdx.x * 64 + w * 16;
  int lr = lane & 15, lk = lane >> 4;

  const short* qrow = (const short*)qb + ((size_t)b*NN + t0 + lr)*64 + lk*8;
  short8 a0 = *(const short8*)qrow;
  short8 a1 = *(const short8*)(qrow + 32);
  const short* kp = (const short*)kb + ((size_t)b*NN + jc*512 + lr)*64 + lk*8;

  short8 n00 = *(const short8*)kp;
  short8 n01 = *(const short8*)(kp + 32);
  short8 n10 = *(const short8*)(kp + 1024);
  short8 n11 = *(const short8*)(kp + 1024 + 32);

  float rs[4] = {0.f, 0.f, 0.f, 0.f};
  float mx[4] = {-3e38f, -3e38f, -3e38f, -3e38f};
#pragma unroll 2
  for (int j = 0; j < 512; j += 32) {
    short8 b00 = n00, b01 = n01, b10 = n10, b11 = n11;
    kp += 32*64;
    if (j + 32 < 512) {
      n00 = *(const short8*)kp;
      n01 = *(const short8*)(kp + 32);
      n10 = *(const short8*)(kp + 1024);
      n11 = *(const short8*)(kp + 1024 + 32);
    }
    f32x4 d0 = {0.f,0.f,0.f,0.f}, d1 = {0.f,0.f,0.f,0.f};
    d0 = __builtin_amdgcn_mfma_f32_16x16x32_bf16(a0, b00, d0, 0, 0, 0);
    d0 = __builtin_amdgcn_mfma_f32_16x16x32_bf16(a1, b01, d0, 0, 0, 0);
    d1 = __builtin_amdgcn_mfma_f32_16x16x32_bf16(a0, b10, d1, 0, 0, 0);
    d1 = __builtin_amdgcn_mfma_f32_16x16x32_bf16(a1, b11, d1, 0, 0, 0);
#pragma unroll
    for (int r = 0; r < 4; ++r) {
      rs[r] += exp2f(d0[r]) + exp2f(d1[r]);
      mx[r] = fmaxf(mx[r], fmaxf(d0[r], d1[r]));
    }
  }
#pragma unroll
  for (int r = 0; r < 4; ++r) {
#pragma unroll
    for (int m = 1; m < 16; m <<= 1) {
      rs[r] += __shfl_xor(rs[r], m, 64);
      mx[r] = fmaxf(mx[r], __shfl_xor(mx[r], m, 64));
    }
  }
  if (lr == 0) {
    size_t base = (size_t)jc*(NB*NN) + (size_t)b*NN + t0 + lk*4;
#pragma unroll
    for (int r = 0; r < 4; ++r) {
      Lpart[base + r] = rs[r];
      Mpart[base + r] = mx[r];
    }
  }
}

// ---------------- K3b: reduce L, M; gateL = sum_t exp2(M_t)/L_t -------------------
__global__ __launch_bounds__(256) void k_Lred(const float* __restrict__ Lpart,
                                              const float* __restrict__ Mpart,
                                              const float* __restrict__ gateN,
                                              float* __restrict__ L,
                                              float* __restrict__ gateL) {
  if (F_DT * gateN[0] < 0.99f) return;
  int i = blockIdx.x * 256 + threadIdx.x;   // 16384
  float sum = 0.f, mx = -3e38f;
#pragma unroll
  for (int jc = 0; jc < 8; ++jc) {
    sum += Lpart[(size_t)jc*(NB*NN) + i];
    mx = fmaxf(mx, Mpart[(size_t)jc*(NB*NN) + i]);
  }
  L[i] = sum;
  float m = exp2f(mx) / sum;
  __shared__ float red[256];
  red[threadIdx.x] = m;
  __syncthreads();
  for (int s = 128; s > 0; s >>= 1) {
    if (threadIdx.x < s) red[threadIdx.x] += red[threadIdx.x + s];
    __syncthreads();
  }
  if (threadIdx.x == 0) atomicAdd(gateL, red[0]);
}

// ---------------- K5: spike fallback (exact serial walk; doubly gated) ------------
__global__ __launch_bounds__(256) void k_spike_fb(const __hip_bfloat16* __restrict__ qb,
                                                  const __hip_bfloat16* __restrict__ kb,
                                                  const float* __restrict__ L,
                                                  const float* __restrict__ gateN,
                                                  const float* __restrict__ gateL,
                                                  const float* __restrict__ vv,
                                                  float* __restrict__ out) {
  if (F_DT * gateN[0] < 0.99f) return;    // cheap bound says no spikes
  if (F_DT * gateL[0] < 0.99f) return;    // tight bound says no spikes
  int j = blockIdx.x * 256 + threadIdx.x;
  int b = blockIdx.y;

  float kf[64];
  const __hip_bfloat16* kr = kb + ((size_t)b*NN + j)*64;
#pragma unroll
  for (int c = 0; c < 64; ++c) kf[c] = __bfloat162float(kr[c]);
  const __hip_bfloat16* Qb = qb + (size_t)b*NN*64;
  const float* Lb = L + (size_t)b*NN;
  const float* V  = vv + ((size_t)b*NN + j)*64;

  float cum = 0.f, Fprev = 0.f;
  for (int t = 0; t < NN; ++t) {
    const __hip_bfloat16* qr = Qb + (size_t)t*64;
    float dot = 0.f;
    for (int c = 0; c < 64; ++c) dot += __bfloat162float(qr[c]) * kf[c];
    float r = exp2f(dot) / Lb[t];
    cum += r * F_DT;
    float F = floorf(cum);
    if (F > Fprev) {
      float sv = (F - Fprev) / F_DT;
      float* orow = out + ((size_t)b*NN + t)*NC;
      for (int d = 0; d < NC; ++d) atomicAdd(orow + d, sv * V[d]);
      Fprev = F;
    }
  }
}

extern "C" void kernel_launch(void* const* d_in, const int* in_sizes, int n_in,
                              void* d_out, int out_size, void* d_ws, size_t ws_size,
                              hipStream_t stream) {
  const float* x  = (const float*)d_in[0];
  const float* w1 = (const float*)d_in[1];
  const float* w2 = (const float*)d_in[2];
  const float* g  = (const float*)d_in[3];
  const float* be = (const float*)d_in[4];
  const float* mu = (const float*)d_in[5];
  const float* va = (const float*)d_in[6];
  float* out = (float*)d_out;
  float* ws  = (float*)d_ws;

  __hip_bfloat16* xp  = (__hip_bfloat16*)(ws + OFF_XP);
  __hip_bfloat16* w1t = (__hip_bfloat16*)(ws + OFF_W1T);
  float*          bi  = ws + OFF_BI;
  __hip_bfloat16* w2t = (__hip_bfloat16*)(ws + OFF_W2T);
  __hip_bfloat16* t1p = (__hip_bfloat16*)(ws + OFF_T1P);
  __hip_bfloat16* qb  = (__hip_bfloat16*)(ws + OFF_QB);
  __hip_bfloat16* kb  = (__hip_bfloat16*)(ws + OFF_KB);
  float* vv  = ws + OFF_VV;
  float* Lp  = ws + OFF_LP;
  float* Mp  = ws + OFF_MP;
  float* L   = ws + OFF_L;
  float* gtL = ws + OFF_GT;
  float* qn2 = ws + OFF_QN2;
  int*   kmx = (int*)(ws + OFF_KMX);
  float* gtN = ws + OFF_GN;

  k_xprep <<<dim3(4488), dim3(256), 0, stream>>>(x, xp);
  k_wprep <<<dim3(87),   dim3(256), 0, stream>>>(w1, w2, g, be, mu, va, w1t, bi, w2t);
  k_zstrip<<<dim3(1536), dim3(256), 0, stream>>>(t1p);
  k_zero  <<<dim3(800),  dim3(1024), 0, stream>>>(out, gtL, gtN, kmx);
  k_conv1m<<<dim3(31, 12), dim3(256), 0, stream>>>(xp, w1t, bi, t1p);
  k_conv2m<<<dim3(32, 12), dim3(256), 0, stream>>>(t1p, w2t, qb, kb, vv);
  k_gateA <<<dim3(64), dim3(256), 0, stream>>>(qb, kb, qn2, kmx);
  k_gateB <<<dim3(64), dim3(256), 0, stream>>>(qn2, kmx, gtN);
  k_L     <<<dim3(64, 8, NB), dim3(256), 0, stream>>>(qb, kb, gtN, Lp, Mp);
  k_Lred  <<<dim3(64), dim3(256), 0, stream>>>(Lp, Mp, gtN, L, gtL);
  k_spike_fb<<<dim3(16, NB), dim3(256), 0, stream>>>(qb, kb, L, gtN, gtL, vv, out);
}